// Round 5
// baseline (6385.358 us; speedup 1.0000x reference)
//
#include <hip/hip_runtime.h>
#include <math.h>

#define B_   64
#define T_   512
#define IN_  64
#define HID_ 256
#define KTOT 65536   // HID*HID

typedef __attribute__((ext_vector_type(8))) short  short8;
typedef __attribute__((ext_vector_type(4))) float  floatx4;

__device__ __forceinline__ unsigned short f2bf(float f) {
    unsigned int u = __float_as_uint(f);
    u += 0x7FFFu + ((u >> 16) & 1u);          // round-to-nearest-even
    return (unsigned short)(u >> 16);
}
__device__ __forceinline__ float bf2f(unsigned short s) {
    return __uint_as_float(((unsigned int)s) << 16);
}
// fast tanh: |err| ~1e-6, far below bf16 quantization of r
__device__ __forceinline__ float tanh_fast(float x) {
    const float ax = fminf(fabsf(x), 10.0f);
    const float e  = __expf(ax * 2.0f);
    const float r  = (e - 1.0f) * __frcp_rn(e + 1.0f);
    return copysignf(r, x);
}

// coherent (agent-scope, cache-bypassing -> memory-side LLC) accesses
__device__ __forceinline__ void cstore(float* p, float v) {
    __hip_atomic_store(p, v, __ATOMIC_RELAXED, __HIP_MEMORY_SCOPE_AGENT);
}
__device__ __forceinline__ float cload(const float* p) {
    return __hip_atomic_load((float*)p, __ATOMIC_RELAXED, __HIP_MEMORY_SCOPE_AGENT);
}
__device__ __forceinline__ void cstore_u32(unsigned* p, unsigned v) {
    __hip_atomic_store(p, v, __ATOMIC_RELAXED, __HIP_MEMORY_SCOPE_AGENT);
}
__device__ __forceinline__ unsigned long long cload_u64(const unsigned long long* p) {
    return __hip_atomic_load((unsigned long long*)p, __ATOMIC_RELAXED,
                             __HIP_MEMORY_SCOPE_AGENT);
}

// ---- fallback only: W_hh fp32 -> bf16 ------------------------------------
__global__ __launch_bounds__(256) void conv_w(const float* __restrict__ W,
                                              unsigned short* __restrict__ Wb)
{
    const size_t idx = ((size_t)blockIdx.x * 256 + threadIdx.x) * 4;
    const float4 v = *(const float4*)(W + idx);
    unsigned int lo = (unsigned int)f2bf(v.x) | ((unsigned int)f2bf(v.y) << 16);
    unsigned int hi = (unsigned int)f2bf(v.z) | ((unsigned int)f2bf(v.w) << 16);
    *(uint2*)(Wb + idx) = make_uint2(lo, hi);
}

// ---- tier2/fallback init: rB(bf16), W_inT, zero barrier ------------------
__global__ __launch_bounds__(256) void init_kernel(const float* __restrict__ x0,
                                                   const float* __restrict__ W_in,
                                                   unsigned short* __restrict__ rB,
                                                   float* __restrict__ W_inT,
                                                   unsigned* __restrict__ bar)
{
    const int b = blockIdx.x;   // doubles as k for W_inT (both 64)
    const int i = threadIdx.x;
    rB[b * HID_ + i] = f2bf(tanhf(x0[b * HID_ + i]));
    W_inT[b * HID_ + i] = W_in[i * IN_ + b];
    if (b == 0) {
        for (int j2 = i; j2 < 1024; j2 += 256) bar[j2] = 0u;
    }
}

// ---- tier-new init: W_inT + zero barrier ---------------------------------
__global__ __launch_bounds__(256) void init2_kernel(const float* __restrict__ W_in,
                                                    float* __restrict__ W_inT,
                                                    unsigned* __restrict__ bar)
{
    const int b = blockIdx.x;
    const int i = threadIdx.x;
    W_inT[b * HID_ + i] = W_in[i * IN_ + b];
    if (b == 0) {
        for (int j2 = i; j2 < 1024; j2 += 256) bar[j2] = 0u;
    }
}

// ---- zero the H ring (32 MB) ---------------------------------------------
__global__ __launch_bounds__(256) void zero_ws(float* __restrict__ p)
{
    const size_t idx = ((size_t)blockIdx.x * 256 + threadIdx.x) * 4;
    *(float4*)(p + idx) = make_float4(0.f, 0.f, 0.f, 0.f);
}

// fallback-only: x state buffer init
__global__ __launch_bounds__(256) void init_x(const float* __restrict__ x0,
                                              float* __restrict__ x)
{
    const int idx = blockIdx.x * 256 + threadIdx.x;
    x[idx] = x0[idx];
}

// ---- precompute: pre[t][b][i] = 0.05*n + 0.2*(b_in + u@W_in^T) -----------
__global__ __launch_bounds__(256) void pre_kernel(const float* __restrict__ u,
                                                  const float* __restrict__ W_inT,
                                                  const float* __restrict__ b_in,
                                                  const float* __restrict__ noise,
                                                  float* __restrict__ pre)
{
    __shared__ float u_s[4][64];
    const int i  = threadIdx.x;
    const int b  = blockIdx.x >> 2;
    const int t0 = (blockIdx.x & 3) << 7;
    float wcol[64];
    #pragma unroll
    for (int k = 0; k < 64; ++k) wcol[k] = W_inT[(k << 8) + i];
    const float bi = b_in[i];
    for (int tt = 0; tt < 128; tt += 4) {
        __syncthreads();
        u_s[i >> 6][i & 63] = u[b * (T_ * IN_) + (t0 + tt + (i >> 6)) * IN_ + (i & 63)];
        __syncthreads();
        #pragma unroll
        for (int j2 = 0; j2 < 4; ++j2) {
            const int t = t0 + tt + j2;
            float acc = bi;
            #pragma unroll
            for (int k = 0; k < 64; ++k) acc = fmaf(u_s[j2][k], wcol[k], acc);
            pre[t * 16384 + b * HID_ + i] =
                fmaf(0.05f, noise[t * 16384 + b * HID_ + i], 0.2f * acc);
        }
    }
}

// bf16 variant (for tighter workspaces)
__global__ __launch_bounds__(256) void preB_kernel(const float* __restrict__ u,
                                                   const float* __restrict__ W_inT,
                                                   const float* __restrict__ b_in,
                                                   const float* __restrict__ noise,
                                                   unsigned short* __restrict__ pre)
{
    __shared__ float u_s[4][64];
    const int i  = threadIdx.x;
    const int b  = blockIdx.x >> 2;
    const int t0 = (blockIdx.x & 3) << 7;
    float wcol[64];
    #pragma unroll
    for (int k = 0; k < 64; ++k) wcol[k] = W_inT[(k << 8) + i];
    const float bi = b_in[i];
    for (int tt = 0; tt < 128; tt += 4) {
        __syncthreads();
        u_s[i >> 6][i & 63] = u[b * (T_ * IN_) + (t0 + tt + (i >> 6)) * IN_ + (i & 63)];
        __syncthreads();
        #pragma unroll
        for (int j2 = 0; j2 < 4; ++j2) {
            const int t = t0 + tt + j2;
            float acc = bi;
            #pragma unroll
            for (int k = 0; k < 64; ++k) acc = fmaf(u_s[j2][k], wcol[k], acc);
            pre[t * 16384 + b * HID_ + i] =
                f2bf(fmaf(0.05f, noise[t * 16384 + b * HID_ + i], 0.2f * acc));
        }
    }
}

// ---- control-only hierarchical grid barrier (16 groups x 32 blocks) ------
#define NGRP  16
#define GRPSZ 32

__device__ __forceinline__ int grid_bar(unsigned* bar, int gid, unsigned ep,
                                        int* abort_s)
{
    __syncthreads();                     // drains vmcnt: stores/atomics retired
    if (threadIdx.x == 0) {
        int poison = 0;
        const unsigned a = __hip_atomic_fetch_add(&bar[gid * 32], 1u,
                               __ATOMIC_RELAXED, __HIP_MEMORY_SCOPE_AGENT);
        if (a == ep * GRPSZ - 1u) {      // last block of group
            const unsigned r = __hip_atomic_fetch_add(&bar[512], 1u,
                                   __ATOMIC_RELAXED, __HIP_MEMORY_SCOPE_AGENT);
            if (r == ep * NGRP - 1u) {   // last group: release
                __hip_atomic_store(&bar[544], ep, __ATOMIC_RELAXED,
                                   __HIP_MEMORY_SCOPE_AGENT);
            }
        }
        unsigned spins = 0;
        for (;;) {
            const unsigned f = __hip_atomic_load(&bar[544], __ATOMIC_RELAXED,
                                                 __HIP_MEMORY_SCOPE_AGENT);
            if (f >= ep) break;
            if ((spins & 63u) == 0u) {
                if (__hip_atomic_load(&bar[560], __ATOMIC_RELAXED,
                                      __HIP_MEMORY_SCOPE_AGENT) != 0u) {
                    poison = 1; break;
                }
            }
            if (++spins > 1000000u) {    // bounded: poison all, abort cleanly
                __hip_atomic_store(&bar[560], 1u, __ATOMIC_RELAXED,
                                   __HIP_MEMORY_SCOPE_AGENT);
                poison = 1; break;
            }
            __builtin_amdgcn_s_sleep(1);
        }
        *abort_s = poison;
    }
    __syncthreads();
    return *abort_s;
}

// ---- NEW persistent kernel: ONE barrier per step -------------------------
// 512 blocks x 256 thr, 2 blocks/CU. Block (ig,kg): i-range [ig*16,+16),
// j-range [kg*8,+8); W slice in VGPR (wv[16] = 64 regs/lane).
// Per step: G: MFMA over local rL -> Wr in-block reduce -> wave0 atomicAdds
// 1024 partials into H[t] (write-once-per-address ring, pre-zeroed).
// ONE grid barrier. Then EVERY block plain-loads H[t] (cold addresses ->
// fresh; XCD L2 amplifies 64x), redundantly updates the FULL x state held
// in registers (64 pairs/thread), writes r(t+1) into its own LDS tile.
// No ring exchange, no P buffer, no second barrier. Owner slice -> traj/xf.
__global__ __launch_bounds__(256, 2) void persist2(
    const float* __restrict__ W_hh,
    float* __restrict__ H,                  // [512][16384], pre-zeroed
    const float* __restrict__ preF,         // f32 pre (if !preBf16)
    const unsigned short* __restrict__ preH,// bf16 pre (if preBf16)
    const float* __restrict__ x0,
    float* __restrict__ traj,
    float* __restrict__ xf,
    unsigned* bar,
    int preBf16)
{
    __shared__ unsigned short rL[16384];     // 32 KB swizzled r[64 b][256 k]
    __shared__ float Wr[3][4][64][4];        // 12 KB wave partials
    __shared__ int abort_s;

    const int tid = threadIdx.x;
    const int l   = tid & 63;
    const int w   = tid >> 6;        // wave 0..3
    const int m   = l & 15;
    const int q   = l >> 4;
    const int blk = blockIdx.x;
    const int ig  = blk >> 5;        // i-group 0..15
    const int kg  = blk & 31;        // j-group 0..31
    const int i0  = ig << 4;
    const int j0  = (kg << 3) + (w << 1);   // this wave's even j

    // ---- W residency: fp32 -> bf16 into 16 x short8 (64 VGPR) ----
    short8 wv[16];
    {
        const float* s0 = W_hh + (size_t)(i0 + m) * KTOT + (j0 << 8) + (q << 3);
        #pragma unroll
        for (int kc = 0; kc < 8; ++kc) {
            #pragma unroll
            for (int half = 0; half < 2; ++half) {
                const float* sp = s0 + (half << 8) + (kc << 5);
                const float4 a  = *(const float4*)(sp);
                const float4 bv = *(const float4*)(sp + 4);
                unsigned* gp = (unsigned*)&wv[kc + (half << 3)];
                gp[0] = (unsigned)f2bf(a.x)  | ((unsigned)f2bf(a.y)  << 16);
                gp[1] = (unsigned)f2bf(a.z)  | ((unsigned)f2bf(a.w)  << 16);
                gp[2] = (unsigned)f2bf(bv.x) | ((unsigned)f2bf(bv.y) << 16);
                gp[3] = (unsigned)f2bf(bv.z) | ((unsigned)f2bf(bv.w) << 16);
            }
        }
    }

    // ---- x-state ownership: thread holds pairs (b = bh+8e, i = il..il+7) --
    const int bh = tid >> 5;          // 0..7
    const int il = (tid & 31) << 3;   // 0..248
    float xreg[64];                   // xreg[e*8+j]
    #pragma unroll
    for (int e = 0; e < 8; ++e) {
        const int b = bh + (e << 3);
        const float4 a = *(const float4*)(x0 + (b << 8) + il);
        const float4 c = *(const float4*)(x0 + (b << 8) + il + 4);
        xreg[(e << 3) + 0] = a.x; xreg[(e << 3) + 1] = a.y;
        xreg[(e << 3) + 2] = a.z; xreg[(e << 3) + 3] = a.w;
        xreg[(e << 3) + 4] = c.x; xreg[(e << 3) + 5] = c.y;
        xreg[(e << 3) + 6] = c.z; xreg[(e << 3) + 7] = c.w;
        short8 fr; unsigned* gp = (unsigned*)&fr;
        #pragma unroll
        for (int p = 0; p < 4; ++p)
            gp[p] = (unsigned)f2bf(tanh_fast(xreg[(e << 3) + 2 * p])) |
                    ((unsigned)f2bf(tanh_fast(xreg[(e << 3) + 2 * p + 1])) << 16);
        *(short8*)&rL[(b << 8) + (il ^ ((b & 7) << 3))] = fr;
    }
    __syncthreads();

    // traj owner: block blk owns pairs [blk*32, +32) = (b=blk>>3, i in 32-range)
    const int ob   = blk >> 3;
    const int oe   = ob >> 3;
    const bool iown = ((tid >> 5) == (ob & 7)) &&
                      ((tid & 31) >= ((blk & 7) << 2)) &&
                      ((tid & 31) <  ((blk & 7) << 2) + 4);
    const int gid = blk >> 5;
    const floatx4 z4 = {0.f, 0.f, 0.f, 0.f};

    for (int t = 0; t < T_; ++t) {
        // ================= G: MFMA over 2 j's =================
        floatx4 aA[4], aB[4];
        #pragma unroll
        for (int mt = 0; mt < 4; ++mt) { aA[mt] = z4; aB[mt] = z4; }
        #pragma unroll
        for (int kc = 0; kc < 8; ++kc) {
            const int cc = (q << 3) + (kc << 5);
            #pragma unroll
            for (int mt = 0; mt < 4; ++mt) {
                const int row = (mt << 4) + m;
                const short8 af = *(const short8*)&rL[(row << 8) + (cc ^ ((row & 7) << 3))];
                aA[mt] = __builtin_amdgcn_mfma_f32_16x16x32_bf16(af, wv[kc],     aA[mt], 0, 0, 0);
                aB[mt] = __builtin_amdgcn_mfma_f32_16x16x32_bf16(af, wv[kc + 8], aB[mt], 0, 0, 0);
            }
        }
        // output-side r_j scaling (fp32)
        floatx4 pd[4];
        #pragma unroll
        for (int mt = 0; mt < 4; ++mt) {
            #pragma unroll
            for (int reg = 0; reg < 4; ++reg) {
                const int b = (mt << 4) + (q << 2) + reg;
                const unsigned rr = *(const unsigned*)&rL[(b << 8) + (j0 ^ ((b & 7) << 3))];
                pd[mt][reg] = bf2f((unsigned short)(rr & 0xffffu)) * aA[mt][reg]
                            + bf2f((unsigned short)(rr >> 16))     * aB[mt][reg];
            }
        }
        // in-block cross-wave reduce, then 1024 atomicAdds into H[t]
        if (w > 0) {
            #pragma unroll
            for (int mt = 0; mt < 4; ++mt) *(floatx4*)&Wr[w - 1][mt][l][0] = pd[mt];
        }
        __syncthreads();
        if (w == 0) {
            float* Ht = H + ((size_t)t << 14);
            #pragma unroll
            for (int mt = 0; mt < 4; ++mt) {
                floatx4 s = pd[mt];
                s += *(const floatx4*)&Wr[0][mt][l][0];
                s += *(const floatx4*)&Wr[1][mt][l][0];
                s += *(const floatx4*)&Wr[2][mt][l][0];
                #pragma unroll
                for (int reg = 0; reg < 4; ++reg) {
                    const int b = (mt << 4) + (q << 2) + reg;
                    atomicAdd(&Ht[(b << 8) + i0 + m], s[reg]);
                }
            }
        }

        if (grid_bar(bar, gid, (unsigned)(t + 1), &abort_s)) break;

        // ================= redundant local state update =================
        const float* Ht = H + ((size_t)t << 14);
        #pragma unroll
        for (int e = 0; e < 8; ++e) {
            const int b = bh + (e << 3);
            const float4 h0 = *(const float4*)(Ht + (b << 8) + il);
            const float4 h1 = *(const float4*)(Ht + (b << 8) + il + 4);
            float pv[8];
            if (preBf16) {
                const uint4 pr = *(const uint4*)(preH + ((size_t)t << 14) + (b << 8) + il);
                const unsigned* pu = (const unsigned*)&pr;
                #pragma unroll
                for (int p = 0; p < 4; ++p) {
                    pv[2 * p]     = bf2f((unsigned short)(pu[p] & 0xffffu));
                    pv[2 * p + 1] = bf2f((unsigned short)(pu[p] >> 16));
                }
            } else {
                const float* pf = preF + ((size_t)t << 14) + (b << 8) + il;
                const float4 p0 = *(const float4*)pf;
                const float4 p1 = *(const float4*)(pf + 4);
                pv[0] = p0.x; pv[1] = p0.y; pv[2] = p0.z; pv[3] = p0.w;
                pv[4] = p1.x; pv[5] = p1.y; pv[6] = p1.z; pv[7] = p1.w;
            }
            const float hh[8] = {h0.x, h0.y, h0.z, h0.w, h1.x, h1.y, h1.z, h1.w};
            short8 fr; unsigned* gp = (unsigned*)&fr;
            #pragma unroll
            for (int jj = 0; jj < 8; ++jj) {
                const float xn = fmaf(0.8f, xreg[(e << 3) + jj],
                                      fmaf(0.2f, hh[jj], pv[jj]));
                xreg[(e << 3) + jj] = xn;
            }
            #pragma unroll
            for (int p = 0; p < 4; ++p)
                gp[p] = (unsigned)f2bf(tanh_fast(xreg[(e << 3) + 2 * p])) |
                        ((unsigned)f2bf(tanh_fast(xreg[(e << 3) + 2 * p + 1])) << 16);
            *(short8*)&rL[(b << 8) + (il ^ ((b & 7) << 3))] = fr;
        }
        // owner writes traj (and xf at the end)
        if (iown) {
            float* tp = traj + (size_t)ob * (T_ * HID_) + (t << 8) + il;
            const float4 o0 = {xreg[(oe << 3) + 0], xreg[(oe << 3) + 1],
                               xreg[(oe << 3) + 2], xreg[(oe << 3) + 3]};
            const float4 o1 = {xreg[(oe << 3) + 4], xreg[(oe << 3) + 5],
                               xreg[(oe << 3) + 6], xreg[(oe << 3) + 7]};
            *(float4*)tp = o0; *(float4*)(tp + 4) = o1;
            if (t == T_ - 1) {
                float* xp = xf + (ob << 8) + il;
                *(float4*)xp = o0; *(float4*)(xp + 4) = o1;
            }
        }
        __syncthreads();   // rL(t+1) ready for next G
    }
}

// ======== tier2: R4 persistent kernel (proven, 6.1 ms) — verbatim =========
__global__ __launch_bounds__(256, 2) void persist_kernel(
    const float* __restrict__ W_hh,
    unsigned short* __restrict__ ring,   // 513 slots x 16384 ushorts
    float* __restrict__ P,               // [32][64][256] f32
    const float* __restrict__ pre,
    const float* __restrict__ u,
    const float* __restrict__ W_inT,
    const float* __restrict__ b_in,
    const float* __restrict__ noise,
    const float* __restrict__ x0,
    float* __restrict__ traj,
    float* __restrict__ xf,
    unsigned* bar,
    int use_pre)
{
    __shared__ unsigned short rL[16384];
    __shared__ float Wr[3][4][64][4];
    __shared__ float red[128];
    __shared__ int abort_s;

    const int tid = threadIdx.x;
    const int l   = tid & 63;
    const int w   = tid >> 6;
    const int m   = l & 15;
    const int q   = l >> 4;
    const int blk = blockIdx.x;
    const int ig  = blk >> 5;
    const int kg  = blk & 31;
    const int i0  = ig << 4;
    const int j0  = (kg << 3) + (w << 1);

    short8 wv[16];
    {
        const float* s0 = W_hh + (size_t)(i0 + m) * KTOT + (j0 << 8) + (q << 3);
        #pragma unroll
        for (int kc = 0; kc < 8; ++kc) {
            #pragma unroll
            for (int half = 0; half < 2; ++half) {
                const float* sp = s0 + (half << 8) + (kc << 5);
                const float4 a = *(const float4*)(sp);
                const float4 bv = *(const float4*)(sp + 4);
                unsigned* gp = (unsigned*)&wv[kc + (half << 3)];
                gp[0] = (unsigned)f2bf(a.x)  | ((unsigned)f2bf(a.y)  << 16);
                gp[1] = (unsigned)f2bf(a.z)  | ((unsigned)f2bf(a.w)  << 16);
                gp[2] = (unsigned)f2bf(bv.x) | ((unsigned)f2bf(bv.y) << 16);
                gp[3] = (unsigned)f2bf(bv.z) | ((unsigned)f2bf(bv.w) << 16);
            }
        }
    }

    const int own   = tid & 31;
    const int pair0 = blk << 5;
    const int sgrp  = tid >> 5;
    const int cb    = (pair0 + own) >> 8;
    const int ci    = (pair0 + own) & 255;
    float x_reg = x0[pair0 + own];

    const int gid = blk >> 5;
    const floatx4 z4 = {0.f, 0.f, 0.f, 0.f};

    for (int t = 0; t < T_; ++t) {
        {
            unsigned long long* src = (unsigned long long*)(ring + (size_t)t * 16384);
            #pragma unroll
            for (int j2 = 0; j2 < 16; ++j2) {
                const int u2 = (j2 << 8) + tid;
                const unsigned long long v = cload_u64(&src[u2]);
                const int row = u2 >> 6;
                const int c4  = (u2 & 63) << 2;
                *(unsigned long long*)&rL[(row << 8) + (c4 ^ ((row & 7) << 3))] = v;
            }
        }
        __syncthreads();

        floatx4 aA[4], aB[4];
        #pragma unroll
        for (int mt = 0; mt < 4; ++mt) { aA[mt] = z4; aB[mt] = z4; }

        #pragma unroll
        for (int kc = 0; kc < 8; ++kc) {
            const int cc = (q << 3) + (kc << 5);
            #pragma unroll
            for (int mt = 0; mt < 4; ++mt) {
                const int row = (mt << 4) + m;
                const short8 af = *(const short8*)&rL[(row << 8) + (cc ^ ((row & 7) << 3))];
                aA[mt] = __builtin_amdgcn_mfma_f32_16x16x32_bf16(af, wv[kc],     aA[mt], 0, 0, 0);
                aB[mt] = __builtin_amdgcn_mfma_f32_16x16x32_bf16(af, wv[kc + 8], aB[mt], 0, 0, 0);
            }
        }

        floatx4 pd[4];
        #pragma unroll
        for (int mt = 0; mt < 4; ++mt) {
            #pragma unroll
            for (int reg = 0; reg < 4; ++reg) {
                const int b = (mt << 4) + (q << 2) + reg;
                const unsigned rr = *(const unsigned*)&rL[(b << 8) + (j0 ^ ((b & 7) << 3))];
                pd[mt][reg] = bf2f((unsigned short)(rr & 0xffffu)) * aA[mt][reg]
                            + bf2f((unsigned short)(rr >> 16))     * aB[mt][reg];
            }
        }

        if (w > 0) {
            #pragma unroll
            for (int mt = 0; mt < 4; ++mt) *(floatx4*)&Wr[w - 1][mt][l][0] = pd[mt];
        }
        __syncthreads();
        if (w == 0) {
            #pragma unroll
            for (int mt = 0; mt < 4; ++mt) {
                floatx4 s = pd[mt];
                s += *(const floatx4*)&Wr[0][mt][l][0];
                s += *(const floatx4*)&Wr[1][mt][l][0];
                s += *(const floatx4*)&Wr[2][mt][l][0];
                #pragma unroll
                for (int reg = 0; reg < 4; ++reg) {
                    const int b = (mt << 4) + (q << 2) + reg;
                    cstore(&P[(kg << 14) + (b << 8) + i0 + m], s[reg]);
                }
            }
        }

        if (grid_bar(bar, gid, (unsigned)(2 * t + 1), &abort_s)) break;

        {
            const float* Pp = P + (size_t)(sgrp << 2) * 16384 + pair0 + own;
            float part = cload(Pp) + cload(Pp + 16384)
                       + cload(Pp + 2 * 16384) + cload(Pp + 3 * 16384);
            part += __shfl_xor(part, 32, 64);
            if ((tid & 32) == 0) red[(w << 5) + own] = part;
            __syncthreads();
            const float hidden = red[own] + red[32 + own] + red[64 + own] + red[96 + own];

            float pn;
            if (use_pre) {
                pn = pre[(t << 14) + pair0 + own];
            } else {
                float inp = b_in[ci];
                const float* ur = u + cb * (T_ * IN_) + (t << 6);
                #pragma unroll
                for (int k = 0; k < 64; ++k)
                    inp = fmaf(ur[k], W_inT[(k << 8) + ci], inp);
                pn = fmaf(0.05f, noise[((size_t)t << 14) + pair0 + own], 0.2f * inp);
            }
            const float xn = fmaf(0.8f, x_reg, fmaf(0.2f, hidden, pn));
            x_reg = xn;

            const unsigned short rb = f2bf(tanhf(xn));
            const unsigned nb = (unsigned)__shfl_xor((int)(unsigned)rb, 1, 64);
            if (tid < 32) {
                traj[(size_t)cb * (T_ * HID_) + (t << 8) + ci] = xn;
                if ((own & 1) == 0) {
                    cstore_u32((unsigned*)(ring + (size_t)(t + 1) * 16384)
                                   + ((pair0 + own) >> 1),
                               ((unsigned)rb) | (nb << 16));
                }
                if (t == T_ - 1) xf[pair0 + own] = xn;
            }
        }

        if (grid_bar(bar, gid, (unsigned)(2 * t + 2), &abort_s)) break;
    }
}

// ======================= fallback path (known-good) =======================
__global__ __launch_bounds__(256) void gemm_step(const unsigned short* __restrict__ Wb,
                                                 const unsigned short* __restrict__ rB,
                                                 float* __restrict__ P)
{
    __shared__ unsigned short A_lds[32768];

    const int tid = threadIdx.x;
    const int l   = tid & 63;
    const int w   = tid >> 6;
    const int m   = l & 15;
    const int q   = l >> 4;
    const int ig  = blockIdx.x >> 7;
    const int c   = blockIdx.x & 127;
    const int i0  = ig << 6;

    {
        const unsigned short* src = Wb + (size_t)(i0 + (w << 4) + m) * KTOT
                                       + (c << 9) + (q << 3);
        unsigned short* dst = &A_lds[(w << 13) + (l << 3)];
        #pragma unroll
        for (int kc = 0; kc < 16; ++kc) {
            uint4 v = *(const uint4*)(src + (kc << 5));
            *(uint4*)(dst + (kc << 9)) = v;
        }
    }

    const int b = (w << 4) + m;
    const float rj0 = bf2f(rB[b * HID_ + 2 * c]);
    const float rj1 = bf2f(rB[b * HID_ + 2 * c + 1]);
    const unsigned short* rrow = rB + b * HID_ + (q << 3);

    floatx4 acc0 = {0.f, 0.f, 0.f, 0.f};
    floatx4 acc1 = {0.f, 0.f, 0.f, 0.f};
    floatx4 acc2 = {0.f, 0.f, 0.f, 0.f};
    floatx4 acc3 = {0.f, 0.f, 0.f, 0.f};

    __syncthreads();

    #pragma unroll
    for (int kc = 0; kc < 16; ++kc) {
        const float rj = (kc < 8) ? rj0 : rj1;
        const uint4 rv = *(const uint4*)(rrow + ((kc & 7) << 5));
        short8 gfrag;
        {
            unsigned int* gp = (unsigned int*)&gfrag;
            const unsigned short* rs = (const unsigned short*)&rv;
            #pragma unroll
            for (int p = 0; p < 4; ++p) {
                const float lo = bf2f(rs[2 * p])     * rj;
                const float hi = bf2f(rs[2 * p + 1]) * rj;
                gp[p] = (unsigned int)f2bf(lo) | ((unsigned int)f2bf(hi) << 16);
            }
        }
        const unsigned short* ab = &A_lds[(kc << 9) + (l << 3)];
        const short8 w0 = *(const short8*)(ab);
        const short8 w1 = *(const short8*)(ab + 8192);
        const short8 w2 = *(const short8*)(ab + 16384);
        const short8 w3 = *(const short8*)(ab + 24576);
        acc0 = __builtin_amdgcn_mfma_f32_16x16x32_bf16(gfrag, w0, acc0, 0, 0, 0);
        acc1 = __builtin_amdgcn_mfma_f32_16x16x32_bf16(gfrag, w1, acc1, 0, 0, 0);
        acc2 = __builtin_amdgcn_mfma_f32_16x16x32_bf16(gfrag, w2, acc2, 0, 0, 0);
        acc3 = __builtin_amdgcn_mfma_f32_16x16x32_bf16(gfrag, w3, acc3, 0, 0, 0);
    }

    #pragma unroll
    for (int reg = 0; reg < 4; ++reg) {
        float* dst = P + (c << 14) + ((w << 4) + (q << 2) + reg) * HID_ + i0 + m;
        dst[0]  = acc0[reg];
        dst[16] = acc1[reg];
        dst[32] = acc2[reg];
        dst[48] = acc3[reg];
    }
}

__global__ __launch_bounds__(64) void combine_step(const float* __restrict__ P,
                                                   const float* __restrict__ noise,
                                                   const float* __restrict__ u,
                                                   const float* __restrict__ W_inT,
                                                   const float* __restrict__ b_in,
                                                   float* __restrict__ x,
                                                   unsigned short* __restrict__ rB,
                                                   float* __restrict__ traj,
                                                   int t)
{
    const int b = blockIdx.x >> 2;
    const int i = ((blockIdx.x & 3) << 6) + threadIdx.x;

    __shared__ float u_s[64];
    u_s[threadIdx.x] = u[b * (T_ * IN_) + t * IN_ + threadIdx.x];
    __syncthreads();

    const float* Pp = P + b * HID_ + i;
    float s0 = 0.f, s1 = 0.f, s2 = 0.f, s3 = 0.f;
    #pragma unroll 4
    for (int cc = 0; cc < 128; cc += 4) {
        s0 += Pp[(cc + 0) * 16384];
        s1 += Pp[(cc + 1) * 16384];
        s2 += Pp[(cc + 2) * 16384];
        s3 += Pp[(cc + 3) * 16384];
    }
    const float hidden = (s0 + s1) + (s2 + s3);

    float inp = b_in[i];
    #pragma unroll
    for (int k = 0; k < 64; ++k) inp += u_s[k] * W_inT[k * HID_ + i];

    const float xo = x[b * HID_ + i];
    const float n  = noise[t * (B_ * HID_) + b * HID_ + i];
    const float xn = 0.8f * xo + 0.05f * n + 0.2f * (hidden + inp);

    x[b * HID_ + i] = xn;
    traj[(size_t)b * (T_ * HID_) + t * HID_ + i] = xn;
    rB[b * HID_ + i] = f2bf(tanhf(xn));
}

__global__ __launch_bounds__(256) void copy_xfinal(const float* __restrict__ x,
                                                   float* __restrict__ xf)
{
    const int idx = blockIdx.x * 256 + threadIdx.x;
    xf[idx] = x[idx];
}

// ---- output projection (fp32) --------------------------------------------
__global__ __launch_bounds__(256) void output_kernel(const float* __restrict__ traj,
                                                     const float* __restrict__ W_out,
                                                     const float* __restrict__ b_out,
                                                     float* __restrict__ out)
{
    __shared__ float r_s[16 * 256];
    __shared__ float Wt[64 * 65];

    const int tid = threadIdx.x;
    const int b   = blockIdx.x >> 5;
    const int t0  = (blockIdx.x & 31) << 4;

    #pragma unroll
    for (int r = 0; r < 16; ++r) {
        r_s[r * 256 + tid] = tanhf(traj[(size_t)b * (T_ * HID_) + (t0 + r) * HID_ + tid]);
    }

    const int o  = tid & 63;
    const int rg = tid >> 6;
    float acc0 = b_out[o];
    float acc1 = acc0, acc2 = acc0, acc3 = acc0;

    for (int ib = 0; ib < 4; ++ib) {
        __syncthreads();
        #pragma unroll
        for (int r = 0; r < 16; ++r) {
            const int f  = (r << 8) + tid;
            const int oo = f >> 6;
            const int il = f & 63;
            Wt[il * 65 + oo] = W_out[oo * 256 + (ib << 6) + il];
        }
        __syncthreads();
        #pragma unroll 16
        for (int il = 0; il < 64; ++il) {
            const float ww = Wt[il * 65 + o];
            const int i = (ib << 6) + il;
            acc0 += r_s[(rg * 4 + 0) * 256 + i] * ww;
            acc1 += r_s[(rg * 4 + 1) * 256 + i] * ww;
            acc2 += r_s[(rg * 4 + 2) * 256 + i] * ww;
            acc3 += r_s[(rg * 4 + 3) * 256 + i] * ww;
        }
    }
    float* ob = out + b * (T_ * IN_) + (t0 + (rg << 2)) * IN_ + o;
    ob[0 * IN_] = acc0;
    ob[1 * IN_] = acc1;
    ob[2 * IN_] = acc2;
    ob[3 * IN_] = acc3;
}

extern "C" void kernel_launch(void* const* d_in, const int* in_sizes, int n_in,
                              void* d_out, int out_size, void* d_ws, size_t ws_size,
                              hipStream_t stream)
{
    const float* u     = (const float*)d_in[0];
    const float* x0    = (const float*)d_in[1];
    const float* noise = (const float*)d_in[2];
    const float* W_hh  = (const float*)d_in[3];
    const float* W_in  = (const float*)d_in[4];
    const float* b_in  = (const float*)d_in[5];
    const float* W_out = (const float*)d_in[6];
    const float* b_out = (const float*)d_in[7];

    float* out  = (float*)d_out;
    float* xf   = out + 2097152;            // [B][HID]
    float* traj = out + 2097152 + 16384;    // [B][T][HID]

    char* wsb = (char*)d_ws;

    // ---- tier-new layout: H(32MB) @0, pre @32MB, W_inT+bar after ----
    const size_t preF_bytes = 33554432ull;
    const size_t preH_bytes = 16777216ull;
    const size_t needF32  = 33554432ull + preF_bytes + 65536ull + 4096ull;
    const size_t needBf16 = 33554432ull + preH_bytes + 65536ull + 4096ull;
    const int f32pre = (ws_size >= needF32) ? 1 : 0;
    const int anypre = (f32pre || ws_size >= needBf16) ? 1 : 0;

    if (anypre) {
        const size_t pbytes = f32pre ? preF_bytes : preH_bytes;
        float*          H      = (float*)(wsb);
        float*          preF   = (float*)(wsb + 33554432ull);
        unsigned short* preH   = (unsigned short*)(wsb + 33554432ull);
        float*          W_inT2 = (float*)(wsb + 33554432ull + pbytes);
        unsigned*       bar2   = (unsigned*)(wsb + 33554432ull + pbytes + 65536ull);

        zero_ws<<<8192, 256, 0, stream>>>(H);
        init2_kernel<<<64, 256, 0, stream>>>(W_in, W_inT2, bar2);
        if (f32pre) pre_kernel<<<256, 256, 0, stream>>>(u, W_inT2, b_in, noise, preF);
        else        preB_kernel<<<256, 256, 0, stream>>>(u, W_inT2, b_in, noise, preH);

        const float*          a_W   = W_hh;
        float*                a_H   = H;
        const float*          a_pF  = preF;
        const unsigned short* a_pH  = preH;
        const float*          a_x0  = x0;
        float*                a_tr  = traj;
        float*                a_xf  = xf;
        unsigned*             a_bar = bar2;
        int                   a_bf  = f32pre ? 0 : 1;
        void* args[] = { &a_W, &a_H, &a_pF, &a_pH, &a_x0, &a_tr, &a_xf,
                         &a_bar, &a_bf };
        hipError_t e = hipLaunchCooperativeKernel(persist2, dim3(512), dim3(256),
                                                  args, 0, stream);
        if (e == hipSuccess) {
            output_kernel<<<2048, 256, 0, stream>>>(traj, W_out, b_out, out);
            return;
        }
    }

    // ---- tier2: R4 proven coop layout ----
    {
        float*          P     = (float*)(wsb);
        unsigned short* ring  = (unsigned short*)(wsb + 8388608ull);
        float*          W_inT = (float*)(wsb + 41943040ull);
        unsigned*       bar   = (unsigned*)(wsb + 42008576ull);
        float*          pre   = (float*)(wsb + 42110976ull);
        const int use_pre = (ws_size >= 42110976ull + 33554432ull) ? 1 : 0;

        init_kernel<<<64, 256, 0, stream>>>(x0, W_in, ring, W_inT, bar);
        if (use_pre) pre_kernel<<<256, 256, 0, stream>>>(u, W_inT, b_in, noise, pre);

        const float*          a_W    = W_hh;
        unsigned short*       a_ring = ring;
        float*                a_P    = P;
        const float*          a_pre  = pre;
        const float*          a_u    = u;
        const float*          a_WinT = W_inT;
        const float*          a_bin  = b_in;
        const float*          a_nz   = noise;
        const float*          a_x0   = x0;
        float*                a_traj = traj;
        float*                a_xf   = xf;
        unsigned*             a_bar  = bar;
        int                   a_up   = use_pre;
        void* args[] = { &a_W, &a_ring, &a_P, &a_pre, &a_u, &a_WinT, &a_bin,
                         &a_nz, &a_x0, &a_traj, &a_xf, &a_bar, &a_up };
        hipError_t e = hipLaunchCooperativeKernel(persist_kernel, dim3(512), dim3(256),
                                                  args, 0, stream);
        if (e == hipSuccess) {
            output_kernel<<<2048, 256, 0, stream>>>(traj, W_out, b_out, out);
            return;
        }
    }

    // ---- fallback: per-step launches (known-good path) ----
    {
        float*          P     = (float*)(wsb);
        unsigned short* Wb    = (unsigned short*)(wsb + 8388608ull);
        float*          W_inT = (float*)(wsb + 41943040ull);
        unsigned*       bar   = (unsigned*)(wsb + 42008576ull);
        unsigned short* rB_fb = (unsigned short*)(wsb + 42012672ull);
        float*          x     = (float*)(wsb + 42045440ull);

        conv_w<<<16384, 256, 0, stream>>>(W_hh, Wb);
        init_kernel<<<64, 256, 0, stream>>>(x0, W_in, rB_fb, W_inT, bar);
        init_x<<<64, 256, 0, stream>>>(x0, x);
        for (int t = 0; t < T_; ++t) {
            gemm_step<<<512, 256, 0, stream>>>(Wb, rB_fb, P);
            combine_step<<<256, 64, 0, stream>>>(P, noise, u, W_inT, b_in, x, rB_fb, traj, t);
        }
        copy_xfinal<<<64, 256, 0, stream>>>(x, xf);
        output_kernel<<<2048, 256, 0, stream>>>(traj, W_out, b_out, out);
    }
}

// Round 6
// 5125.784 us; speedup vs baseline: 1.2457x; 1.2457x over previous
//
#include <hip/hip_runtime.h>
#include <math.h>

#define B_   64
#define T_   512
#define IN_  64
#define HID_ 256
#define KTOT 65536   // HID*HID

typedef __attribute__((ext_vector_type(8))) short  short8;
typedef __attribute__((ext_vector_type(4))) float  floatx4;

__device__ __forceinline__ unsigned short f2bf(float f) {
    unsigned int u = __float_as_uint(f);
    u += 0x7FFFu + ((u >> 16) & 1u);          // round-to-nearest-even
    return (unsigned short)(u >> 16);
}
__device__ __forceinline__ float bf2f(unsigned short s) {
    return __uint_as_float(((unsigned int)s) << 16);
}

// coherent (agent-scope, cache-bypassing -> memory-side LLC) accesses
__device__ __forceinline__ void cstore(float* p, float v) {
    __hip_atomic_store(p, v, __ATOMIC_RELAXED, __HIP_MEMORY_SCOPE_AGENT);
}
__device__ __forceinline__ float cload(const float* p) {
    return __hip_atomic_load((float*)p, __ATOMIC_RELAXED, __HIP_MEMORY_SCOPE_AGENT);
}
__device__ __forceinline__ void cstore_u32(unsigned* p, unsigned v) {
    __hip_atomic_store(p, v, __ATOMIC_RELAXED, __HIP_MEMORY_SCOPE_AGENT);
}
__device__ __forceinline__ unsigned long long cload_u64(const unsigned long long* p) {
    return __hip_atomic_load((unsigned long long*)p, __ATOMIC_RELAXED,
                             __HIP_MEMORY_SCOPE_AGENT);
}

// ring slot permutation: bit-reverse(10b) -> consecutive t are >=16MB apart,
// defeating any sequential prefetch that could cache a not-yet-written slot.
__device__ __forceinline__ size_t slot_off(int t) {
    return (size_t)(__brev((unsigned)t) >> 22) << 14;   // ushort offset
}

// ---- fallback only: W_hh fp32 -> bf16 ------------------------------------
__global__ __launch_bounds__(256) void conv_w(const float* __restrict__ W,
                                              unsigned short* __restrict__ Wb)
{
    const size_t idx = ((size_t)blockIdx.x * 256 + threadIdx.x) * 4;
    const float4 v = *(const float4*)(W + idx);
    unsigned int lo = (unsigned int)f2bf(v.x) | ((unsigned int)f2bf(v.y) << 16);
    unsigned int hi = (unsigned int)f2bf(v.z) | ((unsigned int)f2bf(v.w) << 16);
    *(uint2*)(Wb + idx) = make_uint2(lo, hi);
}

// ---- init: rB/ring-slot0 (bf16), W_inT, zero barrier ---------------------
__global__ __launch_bounds__(256) void init_kernel(const float* __restrict__ x0,
                                                   const float* __restrict__ W_in,
                                                   unsigned short* __restrict__ rB,
                                                   float* __restrict__ W_inT,
                                                   unsigned* __restrict__ bar)
{
    const int b = blockIdx.x;   // doubles as k for W_inT (both 64)
    const int i = threadIdx.x;
    rB[b * HID_ + i] = f2bf(tanhf(x0[b * HID_ + i]));
    W_inT[b * HID_ + i] = W_in[i * IN_ + b];
    if (b == 0) {
        for (int j2 = i; j2 < 1024; j2 += 256) bar[j2] = 0u;
    }
}

// fallback-only: x state buffer init
__global__ __launch_bounds__(256) void init_x(const float* __restrict__ x0,
                                              float* __restrict__ x)
{
    const int idx = blockIdx.x * 256 + threadIdx.x;
    x[idx] = x0[idx];
}

// ---- precompute: pre[t][b][i] = 0.05*n + 0.2*(b_in + u@W_in^T) -----------
__global__ __launch_bounds__(256) void pre_kernel(const float* __restrict__ u,
                                                  const float* __restrict__ W_inT,
                                                  const float* __restrict__ b_in,
                                                  const float* __restrict__ noise,
                                                  float* __restrict__ pre)
{
    __shared__ float u_s[4][64];
    const int i  = threadIdx.x;
    const int b  = blockIdx.x >> 2;
    const int t0 = (blockIdx.x & 3) << 7;
    float wcol[64];
    #pragma unroll
    for (int k = 0; k < 64; ++k) wcol[k] = W_inT[(k << 8) + i];
    const float bi = b_in[i];
    for (int tt = 0; tt < 128; tt += 4) {
        __syncthreads();
        u_s[i >> 6][i & 63] = u[b * (T_ * IN_) + (t0 + tt + (i >> 6)) * IN_ + (i & 63)];
        __syncthreads();
        #pragma unroll
        for (int j2 = 0; j2 < 4; ++j2) {
            const int t = t0 + tt + j2;
            float acc = bi;
            #pragma unroll
            for (int k = 0; k < 64; ++k) acc = fmaf(u_s[j2][k], wcol[k], acc);
            pre[t * 16384 + b * HID_ + i] =
                fmaf(0.05f, noise[t * 16384 + b * HID_ + i], 0.2f * acc);
        }
    }
}

// ---- control-only hierarchical grid barrier (16 groups x 32 blocks) ------
#define NGRP  16
#define GRPSZ 32

__device__ __forceinline__ int grid_bar(unsigned* bar, int gid, unsigned ep,
                                        int* abort_s)
{
    __syncthreads();                     // drains vmcnt: stores/atomics retired
    if (threadIdx.x == 0) {
        int poison = 0;
        const unsigned a = __hip_atomic_fetch_add(&bar[gid * 32], 1u,
                               __ATOMIC_RELAXED, __HIP_MEMORY_SCOPE_AGENT);
        if (a == ep * GRPSZ - 1u) {      // last block of group
            const unsigned r = __hip_atomic_fetch_add(&bar[512], 1u,
                                   __ATOMIC_RELAXED, __HIP_MEMORY_SCOPE_AGENT);
            if (r == ep * NGRP - 1u) {   // last group: release
                __hip_atomic_store(&bar[544], ep, __ATOMIC_RELAXED,
                                   __HIP_MEMORY_SCOPE_AGENT);
            }
        }
        unsigned spins = 0;
        for (;;) {
            const unsigned f = __hip_atomic_load(&bar[544], __ATOMIC_RELAXED,
                                                 __HIP_MEMORY_SCOPE_AGENT);
            if (f >= ep) break;
            if ((spins & 63u) == 0u) {
                if (__hip_atomic_load(&bar[560], __ATOMIC_RELAXED,
                                      __HIP_MEMORY_SCOPE_AGENT) != 0u) {
                    poison = 1; break;
                }
            }
            if (++spins > 1000000u) {    // bounded: poison all, abort cleanly
                __hip_atomic_store(&bar[560], 1u, __ATOMIC_RELAXED,
                                   __HIP_MEMORY_SCOPE_AGENT);
                poison = 1; break;
            }
            __builtin_amdgcn_s_sleep(1);
        }
        *abort_s = poison;
    }
    __syncthreads();
    return *abort_s;
}

// ---- persist3: R4 structure + CACHED ring reads (bitrev slots) -----------
// 512 blocks x 256 thr, 2 blocks/CU. Block (ig,kg): i-range [ig*16,+16),
// j-range [kg*8,+8); W slice in VGPR (wv[16] = 64 regs/lane).
// Per step: stage r (ring slot bitrev(t), PLAIN uint4 loads -> L1/L2-served;
// safe: slot written once via cstore, read only after the barrier) into
// swizzled LDS; MFMA over 2 j's, fp32 r_j output scaling; in-block reduce;
// wave0 cstores P[kg] slice. Barrier. Phase C: 4 cloads of P + shfl/LDS
// reduce -> x update -> cstore r into ring slot bitrev(t+1). Barrier.
__global__ __launch_bounds__(256, 2) void persist3(
    const float* __restrict__ W_hh,
    unsigned short* __restrict__ ring,   // 1024 slots x 16384 ushorts (32 MB)
    float* __restrict__ P,               // [32][64][256] f32
    const float* __restrict__ pre,
    const float* __restrict__ u,
    const float* __restrict__ W_inT,
    const float* __restrict__ b_in,
    const float* __restrict__ noise,
    const float* __restrict__ x0,
    float* __restrict__ traj,
    float* __restrict__ xf,
    unsigned* bar,
    int use_pre)
{
    __shared__ unsigned short rL[16384];     // 32 KB swizzled r[64 b][256 k]
    __shared__ float Wr[3][4][64][4];        // 12 KB wave partials
    __shared__ float red[128];
    __shared__ int abort_s;

    const int tid = threadIdx.x;
    const int l   = tid & 63;
    const int w   = tid >> 6;        // wave 0..3
    const int m   = l & 15;
    const int q   = l >> 4;
    const int blk = blockIdx.x;
    const int ig  = blk >> 5;        // i-group 0..15
    const int kg  = blk & 31;        // j-group 0..31
    const int i0  = ig << 4;
    const int j0  = (kg << 3) + (w << 1);   // this wave's even j

    // ---- W residency: fp32 -> bf16 into 16 x short8 (64 VGPR) ----
    short8 wv[16];
    {
        const float* s0 = W_hh + (size_t)(i0 + m) * KTOT + (j0 << 8) + (q << 3);
        #pragma unroll
        for (int kc = 0; kc < 8; ++kc) {
            #pragma unroll
            for (int half = 0; half < 2; ++half) {
                const float* sp = s0 + (half << 8) + (kc << 5);
                const float4 a  = *(const float4*)(sp);
                const float4 bv = *(const float4*)(sp + 4);
                unsigned* gp = (unsigned*)&wv[kc + (half << 3)];
                gp[0] = (unsigned)f2bf(a.x)  | ((unsigned)f2bf(a.y)  << 16);
                gp[1] = (unsigned)f2bf(a.z)  | ((unsigned)f2bf(a.w)  << 16);
                gp[2] = (unsigned)f2bf(bv.x) | ((unsigned)f2bf(bv.y) << 16);
                gp[3] = (unsigned)f2bf(bv.z) | ((unsigned)f2bf(bv.w) << 16);
            }
        }
    }

    // phase-C mapping: block owns pairs [blk*32, blk*32+32)
    const int own   = tid & 31;
    const int pair0 = blk << 5;
    const int sgrp  = tid >> 5;           // 0..7, reads kg-slices [4*sgrp,+4)
    const int cb    = (pair0 + own) >> 8;
    const int ci    = (pair0 + own) & 255;
    float x_reg = x0[pair0 + own];

    const int gid = blk >> 5;
    const floatx4 z4 = {0.f, 0.f, 0.f, 0.f};

    for (int t = 0; t < T_; ++t) {
        // ---- stage r (ring slot bitrev(t)) -> rL; PLAIN cached loads ----
        {
            const uint4* src = (const uint4*)(ring + slot_off(t));
            #pragma unroll
            for (int j2 = 0; j2 < 8; ++j2) {
                const int u4  = (j2 << 8) + tid;       // 0..2047
                const uint4 v = src[u4];
                const int row = u4 >> 5;               // 0..63
                const int c8  = (u4 & 31) << 3;        // ushort col, 8-aligned
                *(uint4*)&rL[(row << 8) + (c8 ^ ((row & 7) << 3))] = v;
            }
        }
        __syncthreads();

        // ---- phase G: D[64][16] partial over j0, j0+1 ----
        floatx4 aA[4], aB[4];
        #pragma unroll
        for (int mt = 0; mt < 4; ++mt) { aA[mt] = z4; aB[mt] = z4; }

        #pragma unroll
        for (int kc = 0; kc < 8; ++kc) {
            const int cc = (q << 3) + (kc << 5);
            #pragma unroll
            for (int mt = 0; mt < 4; ++mt) {
                const int row = (mt << 4) + m;
                const short8 af = *(const short8*)&rL[(row << 8) + (cc ^ ((row & 7) << 3))];
                aA[mt] = __builtin_amdgcn_mfma_f32_16x16x32_bf16(af, wv[kc],     aA[mt], 0, 0, 0);
                aB[mt] = __builtin_amdgcn_mfma_f32_16x16x32_bf16(af, wv[kc + 8], aB[mt], 0, 0, 0);
            }
        }

        // scale by r_j (fp32 output-side) -> per-wave partial
        floatx4 pd[4];
        #pragma unroll
        for (int mt = 0; mt < 4; ++mt) {
            #pragma unroll
            for (int reg = 0; reg < 4; ++reg) {
                const int b = (mt << 4) + (q << 2) + reg;
                const unsigned rr = *(const unsigned*)&rL[(b << 8) + (j0 ^ ((b & 7) << 3))];
                pd[mt][reg] = bf2f((unsigned short)(rr & 0xffffu)) * aA[mt][reg]
                            + bf2f((unsigned short)(rr >> 16))     * aB[mt][reg];
            }
        }

        // cross-wave reduce (waves 1..3 -> LDS, wave 0 sums + cstores P)
        if (w > 0) {
            #pragma unroll
            for (int mt = 0; mt < 4; ++mt) *(floatx4*)&Wr[w - 1][mt][l][0] = pd[mt];
        }
        __syncthreads();
        if (w == 0) {
            #pragma unroll
            for (int mt = 0; mt < 4; ++mt) {
                floatx4 s = pd[mt];
                s += *(const floatx4*)&Wr[0][mt][l][0];
                s += *(const floatx4*)&Wr[1][mt][l][0];
                s += *(const floatx4*)&Wr[2][mt][l][0];
                #pragma unroll
                for (int reg = 0; reg < 4; ++reg) {
                    const int b = (mt << 4) + (q << 2) + reg;
                    cstore(&P[(kg << 14) + (b << 8) + i0 + m], s[reg]);
                }
            }
        }

        if (grid_bar(bar, gid, (unsigned)(2 * t + 1), &abort_s)) break;

        // ---- phase C ----
        {
            const float* Pp = P + (size_t)(sgrp << 2) * 16384 + pair0 + own;
            float part = cload(Pp) + cload(Pp + 16384)
                       + cload(Pp + 2 * 16384) + cload(Pp + 3 * 16384);
            part += __shfl_xor(part, 32, 64);
            if ((tid & 32) == 0) red[(w << 5) + own] = part;
            __syncthreads();
            const float hidden = red[own] + red[32 + own] + red[64 + own] + red[96 + own];

            float pn;
            if (use_pre) {
                pn = pre[(t << 14) + pair0 + own];
            } else {
                float inp = b_in[ci];
                const float* ur = u + cb * (T_ * IN_) + (t << 6);
                #pragma unroll
                for (int k = 0; k < 64; ++k)
                    inp = fmaf(ur[k], W_inT[(k << 8) + ci], inp);
                pn = fmaf(0.05f, noise[((size_t)t << 14) + pair0 + own], 0.2f * inp);
            }
            const float xn = fmaf(0.8f, x_reg, fmaf(0.2f, hidden, pn));
            x_reg = xn;

            const unsigned short rb = f2bf(tanhf(xn));
            const unsigned nb = (unsigned)__shfl_xor((int)(unsigned)rb, 1, 64);
            if (tid < 32) {
                traj[(size_t)cb * (T_ * HID_) + (t << 8) + ci] = xn;
                if ((own & 1) == 0) {
                    cstore_u32((unsigned*)(ring + slot_off(t + 1))
                                   + ((pair0 + own) >> 1),
                               ((unsigned)rb) | (nb << 16));
                }
                if (t == T_ - 1) xf[pair0 + own] = xn;
            }
        }

        if (grid_bar(bar, gid, (unsigned)(2 * t + 2), &abort_s)) break;
    }
}

// ======== tier2: R4 persistent kernel (proven, 6.1 ms) — verbatim =========
__global__ __launch_bounds__(256, 2) void persist_kernel(
    const float* __restrict__ W_hh,
    unsigned short* __restrict__ ring,   // uses first 513 slots linearly
    float* __restrict__ P,
    const float* __restrict__ pre,
    const float* __restrict__ u,
    const float* __restrict__ W_inT,
    const float* __restrict__ b_in,
    const float* __restrict__ noise,
    const float* __restrict__ x0,
    float* __restrict__ traj,
    float* __restrict__ xf,
    unsigned* bar,
    int use_pre)
{
    __shared__ unsigned short rL[16384];
    __shared__ float Wr[3][4][64][4];
    __shared__ float red[128];
    __shared__ int abort_s;

    const int tid = threadIdx.x;
    const int l   = tid & 63;
    const int w   = tid >> 6;
    const int m   = l & 15;
    const int q   = l >> 4;
    const int blk = blockIdx.x;
    const int ig  = blk >> 5;
    const int kg  = blk & 31;
    const int i0  = ig << 4;
    const int j0  = (kg << 3) + (w << 1);

    short8 wv[16];
    {
        const float* s0 = W_hh + (size_t)(i0 + m) * KTOT + (j0 << 8) + (q << 3);
        #pragma unroll
        for (int kc = 0; kc < 8; ++kc) {
            #pragma unroll
            for (int half = 0; half < 2; ++half) {
                const float* sp = s0 + (half << 8) + (kc << 5);
                const float4 a = *(const float4*)(sp);
                const float4 bv = *(const float4*)(sp + 4);
                unsigned* gp = (unsigned*)&wv[kc + (half << 3)];
                gp[0] = (unsigned)f2bf(a.x)  | ((unsigned)f2bf(a.y)  << 16);
                gp[1] = (unsigned)f2bf(a.z)  | ((unsigned)f2bf(a.w)  << 16);
                gp[2] = (unsigned)f2bf(bv.x) | ((unsigned)f2bf(bv.y) << 16);
                gp[3] = (unsigned)f2bf(bv.z) | ((unsigned)f2bf(bv.w) << 16);
            }
        }
    }

    const int own   = tid & 31;
    const int pair0 = blk << 5;
    const int sgrp  = tid >> 5;
    const int cb    = (pair0 + own) >> 8;
    const int ci    = (pair0 + own) & 255;
    float x_reg = x0[pair0 + own];

    const int gid = blk >> 5;
    const floatx4 z4 = {0.f, 0.f, 0.f, 0.f};

    for (int t = 0; t < T_; ++t) {
        {
            unsigned long long* src = (unsigned long long*)(ring + (size_t)t * 16384);
            #pragma unroll
            for (int j2 = 0; j2 < 16; ++j2) {
                const int u2 = (j2 << 8) + tid;
                const unsigned long long v = cload_u64(&src[u2]);
                const int row = u2 >> 6;
                const int c4  = (u2 & 63) << 2;
                *(unsigned long long*)&rL[(row << 8) + (c4 ^ ((row & 7) << 3))] = v;
            }
        }
        __syncthreads();

        floatx4 aA[4], aB[4];
        #pragma unroll
        for (int mt = 0; mt < 4; ++mt) { aA[mt] = z4; aB[mt] = z4; }

        #pragma unroll
        for (int kc = 0; kc < 8; ++kc) {
            const int cc = (q << 3) + (kc << 5);
            #pragma unroll
            for (int mt = 0; mt < 4; ++mt) {
                const int row = (mt << 4) + m;
                const short8 af = *(const short8*)&rL[(row << 8) + (cc ^ ((row & 7) << 3))];
                aA[mt] = __builtin_amdgcn_mfma_f32_16x16x32_bf16(af, wv[kc],     aA[mt], 0, 0, 0);
                aB[mt] = __builtin_amdgcn_mfma_f32_16x16x32_bf16(af, wv[kc + 8], aB[mt], 0, 0, 0);
            }
        }

        floatx4 pd[4];
        #pragma unroll
        for (int mt = 0; mt < 4; ++mt) {
            #pragma unroll
            for (int reg = 0; reg < 4; ++reg) {
                const int b = (mt << 4) + (q << 2) + reg;
                const unsigned rr = *(const unsigned*)&rL[(b << 8) + (j0 ^ ((b & 7) << 3))];
                pd[mt][reg] = bf2f((unsigned short)(rr & 0xffffu)) * aA[mt][reg]
                            + bf2f((unsigned short)(rr >> 16))     * aB[mt][reg];
            }
        }

        if (w > 0) {
            #pragma unroll
            for (int mt = 0; mt < 4; ++mt) *(floatx4*)&Wr[w - 1][mt][l][0] = pd[mt];
        }
        __syncthreads();
        if (w == 0) {
            #pragma unroll
            for (int mt = 0; mt < 4; ++mt) {
                floatx4 s = pd[mt];
                s += *(const floatx4*)&Wr[0][mt][l][0];
                s += *(const floatx4*)&Wr[1][mt][l][0];
                s += *(const floatx4*)&Wr[2][mt][l][0];
                #pragma unroll
                for (int reg = 0; reg < 4; ++reg) {
                    const int b = (mt << 4) + (q << 2) + reg;
                    cstore(&P[(kg << 14) + (b << 8) + i0 + m], s[reg]);
                }
            }
        }

        if (grid_bar(bar, gid, (unsigned)(2 * t + 1), &abort_s)) break;

        {
            const float* Pp = P + (size_t)(sgrp << 2) * 16384 + pair0 + own;
            float part = cload(Pp) + cload(Pp + 16384)
                       + cload(Pp + 2 * 16384) + cload(Pp + 3 * 16384);
            part += __shfl_xor(part, 32, 64);
            if ((tid & 32) == 0) red[(w << 5) + own] = part;
            __syncthreads();
            const float hidden = red[own] + red[32 + own] + red[64 + own] + red[96 + own];

            float pn;
            if (use_pre) {
                pn = pre[(t << 14) + pair0 + own];
            } else {
                float inp = b_in[ci];
                const float* ur = u + cb * (T_ * IN_) + (t << 6);
                #pragma unroll
                for (int k = 0; k < 64; ++k)
                    inp = fmaf(ur[k], W_inT[(k << 8) + ci], inp);
                pn = fmaf(0.05f, noise[((size_t)t << 14) + pair0 + own], 0.2f * inp);
            }
            const float xn = fmaf(0.8f, x_reg, fmaf(0.2f, hidden, pn));
            x_reg = xn;

            const unsigned short rb = f2bf(tanhf(xn));
            const unsigned nb = (unsigned)__shfl_xor((int)(unsigned)rb, 1, 64);
            if (tid < 32) {
                traj[(size_t)cb * (T_ * HID_) + (t << 8) + ci] = xn;
                if ((own & 1) == 0) {
                    cstore_u32((unsigned*)(ring + (size_t)(t + 1) * 16384)
                                   + ((pair0 + own) >> 1),
                               ((unsigned)rb) | (nb << 16));
                }
                if (t == T_ - 1) xf[pair0 + own] = xn;
            }
        }

        if (grid_bar(bar, gid, (unsigned)(2 * t + 2), &abort_s)) break;
    }
}

// ======================= fallback path (known-good) =======================
__global__ __launch_bounds__(256) void gemm_step(const unsigned short* __restrict__ Wb,
                                                 const unsigned short* __restrict__ rB,
                                                 float* __restrict__ P)
{
    __shared__ unsigned short A_lds[32768];

    const int tid = threadIdx.x;
    const int l   = tid & 63;
    const int w   = tid >> 6;
    const int m   = l & 15;
    const int q   = l >> 4;
    const int ig  = blockIdx.x >> 7;
    const int c   = blockIdx.x & 127;
    const int i0  = ig << 6;

    {
        const unsigned short* src = Wb + (size_t)(i0 + (w << 4) + m) * KTOT
                                       + (c << 9) + (q << 3);
        unsigned short* dst = &A_lds[(w << 13) + (l << 3)];
        #pragma unroll
        for (int kc = 0; kc < 16; ++kc) {
            uint4 v = *(const uint4*)(src + (kc << 5));
            *(uint4*)(dst + (kc << 9)) = v;
        }
    }

    const int b = (w << 4) + m;
    const float rj0 = bf2f(rB[b * HID_ + 2 * c]);
    const float rj1 = bf2f(rB[b * HID_ + 2 * c + 1]);
    const unsigned short* rrow = rB + b * HID_ + (q << 3);

    floatx4 acc0 = {0.f, 0.f, 0.f, 0.f};
    floatx4 acc1 = {0.f, 0.f, 0.f, 0.f};
    floatx4 acc2 = {0.f, 0.f, 0.f, 0.f};
    floatx4 acc3 = {0.f, 0.f, 0.f, 0.f};

    __syncthreads();

    #pragma unroll
    for (int kc = 0; kc < 16; ++kc) {
        const float rj = (kc < 8) ? rj0 : rj1;
        const uint4 rv = *(const uint4*)(rrow + ((kc & 7) << 5));
        short8 gfrag;
        {
            unsigned int* gp = (unsigned int*)&gfrag;
            const unsigned short* rs = (const unsigned short*)&rv;
            #pragma unroll
            for (int p = 0; p < 4; ++p) {
                const float lo = bf2f(rs[2 * p])     * rj;
                const float hi = bf2f(rs[2 * p + 1]) * rj;
                gp[p] = (unsigned int)f2bf(lo) | ((unsigned int)f2bf(hi) << 16);
            }
        }
        const unsigned short* ab = &A_lds[(kc << 9) + (l << 3)];
        const short8 w0 = *(const short8*)(ab);
        const short8 w1 = *(const short8*)(ab + 8192);
        const short8 w2 = *(const short8*)(ab + 16384);
        const short8 w3 = *(const short8*)(ab + 24576);
        acc0 = __builtin_amdgcn_mfma_f32_16x16x32_bf16(gfrag, w0, acc0, 0, 0, 0);
        acc1 = __builtin_amdgcn_mfma_f32_16x16x32_bf16(gfrag, w1, acc1, 0, 0, 0);
        acc2 = __builtin_amdgcn_mfma_f32_16x16x32_bf16(gfrag, w2, acc2, 0, 0, 0);
        acc3 = __builtin_amdgcn_mfma_f32_16x16x32_bf16(gfrag, w3, acc3, 0, 0, 0);
    }

    #pragma unroll
    for (int reg = 0; reg < 4; ++reg) {
        float* dst = P + (c << 14) + ((w << 4) + (q << 2) + reg) * HID_ + i0 + m;
        dst[0]  = acc0[reg];
        dst[16] = acc1[reg];
        dst[32] = acc2[reg];
        dst[48] = acc3[reg];
    }
}

__global__ __launch_bounds__(64) void combine_step(const float* __restrict__ P,
                                                   const float* __restrict__ noise,
                                                   const float* __restrict__ u,
                                                   const float* __restrict__ W_inT,
                                                   const float* __restrict__ b_in,
                                                   float* __restrict__ x,
                                                   unsigned short* __restrict__ rB,
                                                   float* __restrict__ traj,
                                                   int t)
{
    const int b = blockIdx.x >> 2;
    const int i = ((blockIdx.x & 3) << 6) + threadIdx.x;

    __shared__ float u_s[64];
    u_s[threadIdx.x] = u[b * (T_ * IN_) + t * IN_ + threadIdx.x];
    __syncthreads();

    const float* Pp = P + b * HID_ + i;
    float s0 = 0.f, s1 = 0.f, s2 = 0.f, s3 = 0.f;
    #pragma unroll 4
    for (int cc = 0; cc < 128; cc += 4) {
        s0 += Pp[(cc + 0) * 16384];
        s1 += Pp[(cc + 1) * 16384];
        s2 += Pp[(cc + 2) * 16384];
        s3 += Pp[(cc + 3) * 16384];
    }
    const float hidden = (s0 + s1) + (s2 + s3);

    float inp = b_in[i];
    #pragma unroll
    for (int k = 0; k < 64; ++k) inp += u_s[k] * W_inT[k * HID_ + i];

    const float xo = x[b * HID_ + i];
    const float n  = noise[t * (B_ * HID_) + b * HID_ + i];
    const float xn = 0.8f * xo + 0.05f * n + 0.2f * (hidden + inp);

    x[b * HID_ + i] = xn;
    traj[(size_t)b * (T_ * HID_) + t * HID_ + i] = xn;
    rB[b * HID_ + i] = f2bf(tanhf(xn));
}

__global__ __launch_bounds__(256) void copy_xfinal(const float* __restrict__ x,
                                                   float* __restrict__ xf)
{
    const int idx = blockIdx.x * 256 + threadIdx.x;
    xf[idx] = x[idx];
}

// ---- output projection (fp32) --------------------------------------------
__global__ __launch_bounds__(256) void output_kernel(const float* __restrict__ traj,
                                                     const float* __restrict__ W_out,
                                                     const float* __restrict__ b_out,
                                                     float* __restrict__ out)
{
    __shared__ float r_s[16 * 256];
    __shared__ float Wt[64 * 65];

    const int tid = threadIdx.x;
    const int b   = blockIdx.x >> 5;
    const int t0  = (blockIdx.x & 31) << 4;

    #pragma unroll
    for (int r = 0; r < 16; ++r) {
        r_s[r * 256 + tid] = tanhf(traj[(size_t)b * (T_ * HID_) + (t0 + r) * HID_ + tid]);
    }

    const int o  = tid & 63;
    const int rg = tid >> 6;
    float acc0 = b_out[o];
    float acc1 = acc0, acc2 = acc0, acc3 = acc0;

    for (int ib = 0; ib < 4; ++ib) {
        __syncthreads();
        #pragma unroll
        for (int r = 0; r < 16; ++r) {
            const int f  = (r << 8) + tid;
            const int oo = f >> 6;
            const int il = f & 63;
            Wt[il * 65 + oo] = W_out[oo * 256 + (ib << 6) + il];
        }
        __syncthreads();
        #pragma unroll 16
        for (int il = 0; il < 64; ++il) {
            const float ww = Wt[il * 65 + o];
            const int i = (ib << 6) + il;
            acc0 += r_s[(rg * 4 + 0) * 256 + i] * ww;
            acc1 += r_s[(rg * 4 + 1) * 256 + i] * ww;
            acc2 += r_s[(rg * 4 + 2) * 256 + i] * ww;
            acc3 += r_s[(rg * 4 + 3) * 256 + i] * ww;
        }
    }
    float* ob = out + b * (T_ * IN_) + (t0 + (rg << 2)) * IN_ + o;
    ob[0 * IN_] = acc0;
    ob[1 * IN_] = acc1;
    ob[2 * IN_] = acc2;
    ob[3 * IN_] = acc3;
}

extern "C" void kernel_launch(void* const* d_in, const int* in_sizes, int n_in,
                              void* d_out, int out_size, void* d_ws, size_t ws_size,
                              hipStream_t stream)
{
    const float* u     = (const float*)d_in[0];
    const float* x0    = (const float*)d_in[1];
    const float* noise = (const float*)d_in[2];
    const float* W_hh  = (const float*)d_in[3];
    const float* W_in  = (const float*)d_in[4];
    const float* b_in  = (const float*)d_in[5];
    const float* W_out = (const float*)d_in[6];
    const float* b_out = (const float*)d_in[7];

    float* out  = (float*)d_out;
    float* xf   = out + 2097152;            // [B][HID]
    float* traj = out + 2097152 + 16384;    // [B][T][HID]

    // ws byte layout (shared by all tiers):
    //   P     : 0           (8 MB region; coop uses first 2 MB)
    //   ring  : 8,388,608   (1024 x 32768 = 33,554,432)  [coop; fb Wb overlaps]
    //   W_inT : 41,943,040  (65,536)
    //   bar   : 42,008,576  (4,096)
    //   rB_fb : 42,012,672  (32,768)                     [fallback]
    //   x_fb  : 42,045,440  (65,536)                     [fallback]
    //   pre   : 42,110,976  (33,554,432)                 [optional]
    char* wsb = (char*)d_ws;
    float*          P     = (float*)(wsb);
    unsigned short* ring  = (unsigned short*)(wsb + 8388608ull);
    unsigned short* Wb    = (unsigned short*)(wsb + 8388608ull);
    float*          W_inT = (float*)(wsb + 41943040ull);
    unsigned*       bar   = (unsigned*)(wsb + 42008576ull);
    unsigned short* rB_fb = (unsigned short*)(wsb + 42012672ull);
    float*          x     = (float*)(wsb + 42045440ull);
    float*          pre   = (float*)(wsb + 42110976ull);
    const int use_pre = (ws_size >= 42110976ull + 33554432ull) ? 1 : 0;

    init_kernel<<<64, 256, 0, stream>>>(x0, W_in, ring, W_inT, bar);
    if (use_pre) pre_kernel<<<256, 256, 0, stream>>>(u, W_inT, b_in, noise, pre);

    // ---- tier1: persist3 (cached ring reads, bitrev slots) ----
    {
        const float*          a_W    = W_hh;
        unsigned short*       a_ring = ring;
        float*                a_P    = P;
        const float*          a_pre  = pre;
        const float*          a_u    = u;
        const float*          a_WinT = W_inT;
        const float*          a_bin  = b_in;
        const float*          a_nz   = noise;
        const float*          a_x0   = x0;
        float*                a_traj = traj;
        float*                a_xf   = xf;
        unsigned*             a_bar  = bar;
        int                   a_up   = use_pre;
        void* args[] = { &a_W, &a_ring, &a_P, &a_pre, &a_u, &a_WinT, &a_bin,
                         &a_nz, &a_x0, &a_traj, &a_xf, &a_bar, &a_up };
        hipError_t e = hipLaunchCooperativeKernel(persist3, dim3(512), dim3(256),
                                                  args, 0, stream);
        if (e == hipSuccess) {
            output_kernel<<<2048, 256, 0, stream>>>(traj, W_out, b_out, out);
            return;
        }
    }

    // ---- tier2: R4 proven coop kernel ----
    {
        const float*          a_W    = W_hh;
        unsigned short*       a_ring = ring;
        float*                a_P    = P;
        const float*          a_pre  = pre;
        const float*          a_u    = u;
        const float*          a_WinT = W_inT;
        const float*          a_bin  = b_in;
        const float*          a_nz   = noise;
        const float*          a_x0   = x0;
        float*                a_traj = traj;
        float*                a_xf   = xf;
        unsigned*             a_bar  = bar;
        int                   a_up   = use_pre;
        void* args[] = { &a_W, &a_ring, &a_P, &a_pre, &a_u, &a_WinT, &a_bin,
                         &a_nz, &a_x0, &a_traj, &a_xf, &a_bar, &a_up };
        hipError_t e = hipLaunchCooperativeKernel(persist_kernel, dim3(512), dim3(256),
                                                  args, 0, stream);
        if (e == hipSuccess) {
            output_kernel<<<2048, 256, 0, stream>>>(traj, W_out, b_out, out);
            return;
        }
    }

    // ---- fallback: per-step launches (known-good path) ----
    {
        conv_w<<<16384, 256, 0, stream>>>(W_hh, Wb);   // clobbers ring
        init_kernel<<<64, 256, 0, stream>>>(x0, W_in, rB_fb, W_inT, bar);
        init_x<<<64, 256, 0, stream>>>(x0, x);
        for (int t = 0; t < T_; ++t) {
            gemm_step<<<512, 256, 0, stream>>>(Wb, rB_fb, P);
            combine_step<<<256, 64, 0, stream>>>(P, noise, u, W_inT, b_in, x, rB_fb, traj, t);
        }
        copy_xfinal<<<64, 256, 0, stream>>>(x, xf);
        output_kernel<<<2048, 256, 0, stream>>>(traj, W_out, b_out, out);
    }
}

// Round 7
// 4740.327 us; speedup vs baseline: 1.3470x; 1.0813x over previous
//
#include <hip/hip_runtime.h>
#include <math.h>

#define B_   64
#define T_   512
#define IN_  64
#define HID_ 256
#define KTOT 65536   // HID*HID

typedef __attribute__((ext_vector_type(8))) short  short8;
typedef __attribute__((ext_vector_type(4))) float  floatx4;

__device__ __forceinline__ unsigned short f2bf(float f) {
    unsigned int u = __float_as_uint(f);
    u += 0x7FFFu + ((u >> 16) & 1u);          // round-to-nearest-even
    return (unsigned short)(u >> 16);
}
__device__ __forceinline__ float bf2f(unsigned short s) {
    return __uint_as_float(((unsigned int)s) << 16);
}

// coherent (agent-scope, cache-bypassing -> memory-side LLC) accesses
__device__ __forceinline__ void cstore(float* p, float v) {
    __hip_atomic_store(p, v, __ATOMIC_RELAXED, __HIP_MEMORY_SCOPE_AGENT);
}
__device__ __forceinline__ float cload(const float* p) {
    return __hip_atomic_load((float*)p, __ATOMIC_RELAXED, __HIP_MEMORY_SCOPE_AGENT);
}
__device__ __forceinline__ void cstore_u32(unsigned* p, unsigned v) {
    __hip_atomic_store(p, v, __ATOMIC_RELAXED, __HIP_MEMORY_SCOPE_AGENT);
}
__device__ __forceinline__ unsigned long long cload_u64(const unsigned long long* p) {
    return __hip_atomic_load((unsigned long long*)p, __ATOMIC_RELAXED,
                             __HIP_MEMORY_SCOPE_AGENT);
}

// ring slot permutation: bit-reverse(10b) -> consecutive t are >=16MB apart,
// defeating any sequential prefetch that could cache a not-yet-written slot.
__device__ __forceinline__ size_t slot_off(int t) {
    return (size_t)(__brev((unsigned)t) >> 22) << 14;   // ushort offset
}

// ---- fallback only: W_hh fp32 -> bf16 ------------------------------------
__global__ __launch_bounds__(256) void conv_w(const float* __restrict__ W,
                                              unsigned short* __restrict__ Wb)
{
    const size_t idx = ((size_t)blockIdx.x * 256 + threadIdx.x) * 4;
    const float4 v = *(const float4*)(W + idx);
    unsigned int lo = (unsigned int)f2bf(v.x) | ((unsigned int)f2bf(v.y) << 16);
    unsigned int hi = (unsigned int)f2bf(v.z) | ((unsigned int)f2bf(v.w) << 16);
    *(uint2*)(Wb + idx) = make_uint2(lo, hi);
}

// ---- init: rB/ring-slot0 (bf16), W_inT, zero barrier (2048 uints) --------
__global__ __launch_bounds__(256) void init_kernel(const float* __restrict__ x0,
                                                   const float* __restrict__ W_in,
                                                   unsigned short* __restrict__ rB,
                                                   float* __restrict__ W_inT,
                                                   unsigned* __restrict__ bar)
{
    const int b = blockIdx.x;   // doubles as k for W_inT (both 64)
    const int i = threadIdx.x;
    rB[b * HID_ + i] = f2bf(tanhf(x0[b * HID_ + i]));
    W_inT[b * HID_ + i] = W_in[i * IN_ + b];
    if (b == 0) {
        for (int j2 = i; j2 < 2048; j2 += 256) bar[j2] = 0u;
    }
}

// fallback-only: x state buffer init
__global__ __launch_bounds__(256) void init_x(const float* __restrict__ x0,
                                              float* __restrict__ x)
{
    const int idx = blockIdx.x * 256 + threadIdx.x;
    x[idx] = x0[idx];
}

// ---- precompute: pre[t][b][i] = 0.05*n + 0.2*(b_in + u@W_in^T) -----------
__global__ __launch_bounds__(256) void pre_kernel(const float* __restrict__ u,
                                                  const float* __restrict__ W_inT,
                                                  const float* __restrict__ b_in,
                                                  const float* __restrict__ noise,
                                                  float* __restrict__ pre)
{
    __shared__ float u_s[4][64];
    const int i  = threadIdx.x;
    const int b  = blockIdx.x >> 2;
    const int t0 = (blockIdx.x & 3) << 7;
    float wcol[64];
    #pragma unroll
    for (int k = 0; k < 64; ++k) wcol[k] = W_inT[(k << 8) + i];
    const float bi = b_in[i];
    for (int tt = 0; tt < 128; tt += 4) {
        __syncthreads();
        u_s[i >> 6][i & 63] = u[b * (T_ * IN_) + (t0 + tt + (i >> 6)) * IN_ + (i & 63)];
        __syncthreads();
        #pragma unroll
        for (int j2 = 0; j2 < 4; ++j2) {
            const int t = t0 + tt + j2;
            float acc = bi;
            #pragma unroll
            for (int k = 0; k < 64; ++k) acc = fmaf(u_s[j2][k], wcol[k], acc);
            pre[t * 16384 + b * HID_ + i] =
                fmaf(0.05f, noise[t * 16384 + b * HID_ + i], 0.2f * acc);
        }
    }
}

// ---- barriers -------------------------------------------------------------
// bar layout (uint idx):
//   [g1*32]        g1<8   : bar1 producer-group counters (64 arrivals each)
//   [256+g1*32]    g1<8   : bar1 group flags
//   [512+g2*32]    g2<16  : bar2 group counters (32 arrivals each)
//   [1024]                : bar2 root counter (16 arrivals)
//   [1056+g2*32]   g2<16  : bar2 distributed release flags
//   [1600]                : poison flag
#define POISON_IDX 1600

__device__ __forceinline__ int spin_flag(unsigned* bar, int flag_idx, unsigned ep)
{
    int poison = 0;
    unsigned spins = 0;
    for (;;) {
        const unsigned f = __hip_atomic_load(&bar[flag_idx], __ATOMIC_RELAXED,
                                             __HIP_MEMORY_SCOPE_AGENT);
        if (f >= ep) break;
        if ((spins & 63u) == 0u) {
            if (__hip_atomic_load(&bar[POISON_IDX], __ATOMIC_RELAXED,
                                  __HIP_MEMORY_SCOPE_AGENT) != 0u) {
                poison = 1; break;
            }
        }
        if (++spins > 1000000u) {    // bounded: poison all, abort cleanly
            __hip_atomic_store(&bar[POISON_IDX], 1u, __ATOMIC_RELAXED,
                               __HIP_MEMORY_SCOPE_AGENT);
            poison = 1; break;
        }
        __builtin_amdgcn_s_sleep(1);
    }
    return poison;
}

// bar1: PARTIAL barrier. Producer group pg = blk>>6 (64 blocks); consumer
// polls group cg = blk&7 (the 64 blocks producing the P slices it reads).
// Single level, 8 flag lines, <=64 pollers/line.
__device__ __forceinline__ int grid_bar1(unsigned* bar, int pg, int cg,
                                         unsigned ep, int* abort_s)
{
    __syncthreads();                     // drains vmcnt: P cstores retired
    if (threadIdx.x == 0) {
        const unsigned a = __hip_atomic_fetch_add(&bar[pg * 32], 1u,
                               __ATOMIC_RELAXED, __HIP_MEMORY_SCOPE_AGENT);
        if (a == ep * 64u - 1u) {
            __hip_atomic_store(&bar[256 + pg * 32], ep, __ATOMIC_RELAXED,
                               __HIP_MEMORY_SCOPE_AGENT);
        }
        *abort_s = spin_flag(bar, 256 + cg * 32, ep);
    }
    __syncthreads();
    return *abort_s;
}

// bar2: GLOBAL barrier with distributed release flags (root leader stores
// 16 per-group flags; members poll only their group's line).
__device__ __forceinline__ int grid_bar2(unsigned* bar, int g2,
                                         unsigned ep, int* abort_s)
{
    __syncthreads();                     // drains vmcnt: ring cstores retired
    if (threadIdx.x == 0) {
        const unsigned a = __hip_atomic_fetch_add(&bar[512 + g2 * 32], 1u,
                               __ATOMIC_RELAXED, __HIP_MEMORY_SCOPE_AGENT);
        if (a == ep * 32u - 1u) {        // last block of group
            const unsigned r = __hip_atomic_fetch_add(&bar[1024], 1u,
                                   __ATOMIC_RELAXED, __HIP_MEMORY_SCOPE_AGENT);
            if (r == ep * 16u - 1u) {    // last group: release all 16 lines
                #pragma unroll
                for (int g = 0; g < 16; ++g)
                    __hip_atomic_store(&bar[1056 + g * 32], ep, __ATOMIC_RELAXED,
                                       __HIP_MEMORY_SCOPE_AGENT);
            }
        }
        *abort_s = spin_flag(bar, 1056 + g2 * 32, ep);
    }
    __syncthreads();
    return *abort_s;
}

// ---- persist4: persist3 data path + decontended barriers + pre prefetch --
// 512 blocks x 256 thr, 2 blocks/CU. Block (ig,kg): i-range [ig*16,+16),
// j-range [kg*8,+8); W slice in VGPR (wv[16] = 64 regs/lane).
// Per step: stage r (ring slot bitrev(t), PLAIN cached uint4 loads; safe:
// slot written once via cstore, read only after the global barrier) into
// swizzled LDS; MFMA over 2 j's, fp32 r_j output scaling; in-block reduce;
// wave0 cstores P[kg] slice. bar1 (partial, dependency-exact). Phase C:
// 4 cloads of P + shfl/LDS reduce -> x update -> cstore r into ring slot
// bitrev(t+1); prefetch pre[t+1]. bar2 (global, distributed flags).
__global__ __launch_bounds__(256, 2) void persist4(
    const float* __restrict__ W_hh,
    unsigned short* __restrict__ ring,   // 1024 slots x 16384 ushorts (32 MB)
    float* __restrict__ P,               // [32][64][256] f32
    const float* __restrict__ pre,
    const float* __restrict__ u,
    const float* __restrict__ W_inT,
    const float* __restrict__ b_in,
    const float* __restrict__ noise,
    const float* __restrict__ x0,
    float* __restrict__ traj,
    float* __restrict__ xf,
    unsigned* bar,
    int use_pre)
{
    __shared__ unsigned short rL[16384];     // 32 KB swizzled r[64 b][256 k]
    __shared__ float Wr[3][4][64][4];        // 12 KB wave partials
    __shared__ float red[128];
    __shared__ int abort_s;

    const int tid = threadIdx.x;
    const int l   = tid & 63;
    const int w   = tid >> 6;        // wave 0..3
    const int m   = l & 15;
    const int q   = l >> 4;
    const int blk = blockIdx.x;
    const int ig  = blk >> 5;        // i-group 0..15
    const int kg  = blk & 31;        // j-group 0..31
    const int i0  = ig << 4;
    const int j0  = (kg << 3) + (w << 1);   // this wave's even j

    // barrier group ids
    const int pg = blk >> 6;         // bar1 producer group (blocks 64pg..+64)
    const int cg = blk & 7;          // bar1 consumed group (P slices it reads)
    const int g2 = blk >> 5;         // bar2 group

    // ---- W residency: fp32 -> bf16 into 16 x short8 (64 VGPR) ----
    short8 wv[16];
    {
        const float* s0 = W_hh + (size_t)(i0 + m) * KTOT + (j0 << 8) + (q << 3);
        #pragma unroll
        for (int kc = 0; kc < 8; ++kc) {
            #pragma unroll
            for (int half = 0; half < 2; ++half) {
                const float* sp = s0 + (half << 8) + (kc << 5);
                const float4 a  = *(const float4*)(sp);
                const float4 bv = *(const float4*)(sp + 4);
                unsigned* gp = (unsigned*)&wv[kc + (half << 3)];
                gp[0] = (unsigned)f2bf(a.x)  | ((unsigned)f2bf(a.y)  << 16);
                gp[1] = (unsigned)f2bf(a.z)  | ((unsigned)f2bf(a.w)  << 16);
                gp[2] = (unsigned)f2bf(bv.x) | ((unsigned)f2bf(bv.y) << 16);
                gp[3] = (unsigned)f2bf(bv.z) | ((unsigned)f2bf(bv.w) << 16);
            }
        }
    }

    // phase-C mapping: block owns pairs [blk*32, blk*32+32)
    const int own   = tid & 31;
    const int pair0 = blk << 5;
    const int sgrp  = tid >> 5;           // 0..7, reads kg-slices [4*sgrp,+4)
    const int cb    = (pair0 + own) >> 8;
    const int ci    = (pair0 + own) & 255;
    float x_reg = x0[pair0 + own];

    const floatx4 z4 = {0.f, 0.f, 0.f, 0.f};

    // prefetch pre[0]
    float pn_pref = 0.f;
    if (use_pre) pn_pref = pre[pair0 + own];

    for (int t = 0; t < T_; ++t) {
        // ---- stage r (ring slot bitrev(t)) -> rL; PLAIN cached loads ----
        {
            const uint4* src = (const uint4*)(ring + slot_off(t));
            #pragma unroll
            for (int j2 = 0; j2 < 8; ++j2) {
                const int u4  = (j2 << 8) + tid;       // 0..2047
                const uint4 v = src[u4];
                const int row = u4 >> 5;               // 0..63
                const int c8  = (u4 & 31) << 3;        // ushort col, 8-aligned
                *(uint4*)&rL[(row << 8) + (c8 ^ ((row & 7) << 3))] = v;
            }
        }
        __syncthreads();

        // ---- phase G: D[64][16] partial over j0, j0+1 ----
        floatx4 aA[4], aB[4];
        #pragma unroll
        for (int mt = 0; mt < 4; ++mt) { aA[mt] = z4; aB[mt] = z4; }

        #pragma unroll
        for (int kc = 0; kc < 8; ++kc) {
            const int cc = (q << 3) + (kc << 5);
            #pragma unroll
            for (int mt = 0; mt < 4; ++mt) {
                const int row = (mt << 4) + m;
                const short8 af = *(const short8*)&rL[(row << 8) + (cc ^ ((row & 7) << 3))];
                aA[mt] = __builtin_amdgcn_mfma_f32_16x16x32_bf16(af, wv[kc],     aA[mt], 0, 0, 0);
                aB[mt] = __builtin_amdgcn_mfma_f32_16x16x32_bf16(af, wv[kc + 8], aB[mt], 0, 0, 0);
            }
        }

        // scale by r_j (fp32 output-side) -> per-wave partial
        floatx4 pd[4];
        #pragma unroll
        for (int mt = 0; mt < 4; ++mt) {
            #pragma unroll
            for (int reg = 0; reg < 4; ++reg) {
                const int b = (mt << 4) + (q << 2) + reg;
                const unsigned rr = *(const unsigned*)&rL[(b << 8) + (j0 ^ ((b & 7) << 3))];
                pd[mt][reg] = bf2f((unsigned short)(rr & 0xffffu)) * aA[mt][reg]
                            + bf2f((unsigned short)(rr >> 16))     * aB[mt][reg];
            }
        }

        // cross-wave reduce (waves 1..3 -> LDS, wave 0 sums + cstores P)
        if (w > 0) {
            #pragma unroll
            for (int mt = 0; mt < 4; ++mt) *(floatx4*)&Wr[w - 1][mt][l][0] = pd[mt];
        }
        __syncthreads();
        if (w == 0) {
            #pragma unroll
            for (int mt = 0; mt < 4; ++mt) {
                floatx4 s = pd[mt];
                s += *(const floatx4*)&Wr[0][mt][l][0];
                s += *(const floatx4*)&Wr[1][mt][l][0];
                s += *(const floatx4*)&Wr[2][mt][l][0];
                #pragma unroll
                for (int reg = 0; reg < 4; ++reg) {
                    const int b = (mt << 4) + (q << 2) + reg;
                    cstore(&P[(kg << 14) + (b << 8) + i0 + m], s[reg]);
                }
            }
        }

        if (grid_bar1(bar, pg, cg, (unsigned)(t + 1), &abort_s)) break;

        // ---- phase C ----
        {
            const float* Pp = P + (size_t)(sgrp << 2) * 16384 + pair0 + own;
            float part = cload(Pp) + cload(Pp + 16384)
                       + cload(Pp + 2 * 16384) + cload(Pp + 3 * 16384);
            part += __shfl_xor(part, 32, 64);
            if ((tid & 32) == 0) red[(w << 5) + own] = part;
            __syncthreads();
            const float hidden = red[own] + red[32 + own] + red[64 + own] + red[96 + own];

            float pn;
            if (use_pre) {
                pn = pn_pref;
            } else {
                float inp = b_in[ci];
                const float* ur = u + cb * (T_ * IN_) + (t << 6);
                #pragma unroll
                for (int k = 0; k < 64; ++k)
                    inp = fmaf(ur[k], W_inT[(k << 8) + ci], inp);
                pn = fmaf(0.05f, noise[((size_t)t << 14) + pair0 + own], 0.2f * inp);
            }
            const float xn = fmaf(0.8f, x_reg, fmaf(0.2f, hidden, pn));
            x_reg = xn;

            const unsigned short rb = f2bf(tanhf(xn));
            const unsigned nb = (unsigned)__shfl_xor((int)(unsigned)rb, 1, 64);
            if (tid < 32) {
                traj[(size_t)cb * (T_ * HID_) + (t << 8) + ci] = xn;
                if ((own & 1) == 0) {
                    cstore_u32((unsigned*)(ring + slot_off(t + 1))
                                   + ((pair0 + own) >> 1),
                               ((unsigned)rb) | (nb << 16));
                }
                if (t == T_ - 1) xf[pair0 + own] = xn;
            }
            // prefetch next step's pre (overlaps bar2 drain + spin)
            if (use_pre && t + 1 < T_) pn_pref = pre[((t + 1) << 14) + pair0 + own];
        }

        if (grid_bar2(bar, g2, (unsigned)(t + 1), &abort_s)) break;
    }
}

// ======== tier2: R4 persistent kernel (proven, 6.1 ms) =====================
__device__ __forceinline__ int grid_bar_old(unsigned* bar, int gid, unsigned ep,
                                            int* abort_s)
{
    __syncthreads();
    if (threadIdx.x == 0) {
        const unsigned a = __hip_atomic_fetch_add(&bar[512 + gid * 32], 1u,
                               __ATOMIC_RELAXED, __HIP_MEMORY_SCOPE_AGENT);
        if (a == ep * 32u - 1u) {
            const unsigned r = __hip_atomic_fetch_add(&bar[1024], 1u,
                                   __ATOMIC_RELAXED, __HIP_MEMORY_SCOPE_AGENT);
            if (r == ep * 16u - 1u) {
                #pragma unroll
                for (int g = 0; g < 16; ++g)
                    __hip_atomic_store(&bar[1056 + g * 32], ep, __ATOMIC_RELAXED,
                                       __HIP_MEMORY_SCOPE_AGENT);
            }
        }
        *abort_s = spin_flag(bar, 1056 + gid * 32, ep);
    }
    __syncthreads();
    return *abort_s;
}

__global__ __launch_bounds__(256, 2) void persist_kernel(
    const float* __restrict__ W_hh,
    unsigned short* __restrict__ ring,   // uses first 513 slots linearly
    float* __restrict__ P,
    const float* __restrict__ pre,
    const float* __restrict__ u,
    const float* __restrict__ W_inT,
    const float* __restrict__ b_in,
    const float* __restrict__ noise,
    const float* __restrict__ x0,
    float* __restrict__ traj,
    float* __restrict__ xf,
    unsigned* bar,
    int use_pre)
{
    __shared__ unsigned short rL[16384];
    __shared__ float Wr[3][4][64][4];
    __shared__ float red[128];
    __shared__ int abort_s;

    const int tid = threadIdx.x;
    const int l   = tid & 63;
    const int w   = tid >> 6;
    const int m   = l & 15;
    const int q   = l >> 4;
    const int blk = blockIdx.x;
    const int ig  = blk >> 5;
    const int kg  = blk & 31;
    const int i0  = ig << 4;
    const int j0  = (kg << 3) + (w << 1);

    short8 wv[16];
    {
        const float* s0 = W_hh + (size_t)(i0 + m) * KTOT + (j0 << 8) + (q << 3);
        #pragma unroll
        for (int kc = 0; kc < 8; ++kc) {
            #pragma unroll
            for (int half = 0; half < 2; ++half) {
                const float* sp = s0 + (half << 8) + (kc << 5);
                const float4 a = *(const float4*)(sp);
                const float4 bv = *(const float4*)(sp + 4);
                unsigned* gp = (unsigned*)&wv[kc + (half << 3)];
                gp[0] = (unsigned)f2bf(a.x)  | ((unsigned)f2bf(a.y)  << 16);
                gp[1] = (unsigned)f2bf(a.z)  | ((unsigned)f2bf(a.w)  << 16);
                gp[2] = (unsigned)f2bf(bv.x) | ((unsigned)f2bf(bv.y) << 16);
                gp[3] = (unsigned)f2bf(bv.z) | ((unsigned)f2bf(bv.w) << 16);
            }
        }
    }

    const int own   = tid & 31;
    const int pair0 = blk << 5;
    const int sgrp  = tid >> 5;
    const int cb    = (pair0 + own) >> 8;
    const int ci    = (pair0 + own) & 255;
    float x_reg = x0[pair0 + own];

    const int gid = blk >> 5;
    const floatx4 z4 = {0.f, 0.f, 0.f, 0.f};

    for (int t = 0; t < T_; ++t) {
        {
            unsigned long long* src = (unsigned long long*)(ring + (size_t)t * 16384);
            #pragma unroll
            for (int j2 = 0; j2 < 16; ++j2) {
                const int u2 = (j2 << 8) + tid;
                const unsigned long long v = cload_u64(&src[u2]);
                const int row = u2 >> 6;
                const int c4  = (u2 & 63) << 2;
                *(unsigned long long*)&rL[(row << 8) + (c4 ^ ((row & 7) << 3))] = v;
            }
        }
        __syncthreads();

        floatx4 aA[4], aB[4];
        #pragma unroll
        for (int mt = 0; mt < 4; ++mt) { aA[mt] = z4; aB[mt] = z4; }

        #pragma unroll
        for (int kc = 0; kc < 8; ++kc) {
            const int cc = (q << 3) + (kc << 5);
            #pragma unroll
            for (int mt = 0; mt < 4; ++mt) {
                const int row = (mt << 4) + m;
                const short8 af = *(const short8*)&rL[(row << 8) + (cc ^ ((row & 7) << 3))];
                aA[mt] = __builtin_amdgcn_mfma_f32_16x16x32_bf16(af, wv[kc],     aA[mt], 0, 0, 0);
                aB[mt] = __builtin_amdgcn_mfma_f32_16x16x32_bf16(af, wv[kc + 8], aB[mt], 0, 0, 0);
            }
        }

        floatx4 pd[4];
        #pragma unroll
        for (int mt = 0; mt < 4; ++mt) {
            #pragma unroll
            for (int reg = 0; reg < 4; ++reg) {
                const int b = (mt << 4) + (q << 2) + reg;
                const unsigned rr = *(const unsigned*)&rL[(b << 8) + (j0 ^ ((b & 7) << 3))];
                pd[mt][reg] = bf2f((unsigned short)(rr & 0xffffu)) * aA[mt][reg]
                            + bf2f((unsigned short)(rr >> 16))     * aB[mt][reg];
            }
        }

        if (w > 0) {
            #pragma unroll
            for (int mt = 0; mt < 4; ++mt) *(floatx4*)&Wr[w - 1][mt][l][0] = pd[mt];
        }
        __syncthreads();
        if (w == 0) {
            #pragma unroll
            for (int mt = 0; mt < 4; ++mt) {
                floatx4 s = pd[mt];
                s += *(const floatx4*)&Wr[0][mt][l][0];
                s += *(const floatx4*)&Wr[1][mt][l][0];
                s += *(const floatx4*)&Wr[2][mt][l][0];
                #pragma unroll
                for (int reg = 0; reg < 4; ++reg) {
                    const int b = (mt << 4) + (q << 2) + reg;
                    cstore(&P[(kg << 14) + (b << 8) + i0 + m], s[reg]);
                }
            }
        }

        if (grid_bar_old(bar, gid, (unsigned)(2 * t + 1), &abort_s)) break;

        {
            const float* Pp = P + (size_t)(sgrp << 2) * 16384 + pair0 + own;
            float part = cload(Pp) + cload(Pp + 16384)
                       + cload(Pp + 2 * 16384) + cload(Pp + 3 * 16384);
            part += __shfl_xor(part, 32, 64);
            if ((tid & 32) == 0) red[(w << 5) + own] = part;
            __syncthreads();
            const float hidden = red[own] + red[32 + own] + red[64 + own] + red[96 + own];

            float pn;
            if (use_pre) {
                pn = pre[(t << 14) + pair0 + own];
            } else {
                float inp = b_in[ci];
                const float* ur = u + cb * (T_ * IN_) + (t << 6);
                #pragma unroll
                for (int k = 0; k < 64; ++k)
                    inp = fmaf(ur[k], W_inT[(k << 8) + ci], inp);
                pn = fmaf(0.05f, noise[((size_t)t << 14) + pair0 + own], 0.2f * inp);
            }
            const float xn = fmaf(0.8f, x_reg, fmaf(0.2f, hidden, pn));
            x_reg = xn;

            const unsigned short rb = f2bf(tanhf(xn));
            const unsigned nb = (unsigned)__shfl_xor((int)(unsigned)rb, 1, 64);
            if (tid < 32) {
                traj[(size_t)cb * (T_ * HID_) + (t << 8) + ci] = xn;
                if ((own & 1) == 0) {
                    cstore_u32((unsigned*)(ring + (size_t)(t + 1) * 16384)
                                   + ((pair0 + own) >> 1),
                               ((unsigned)rb) | (nb << 16));
                }
                if (t == T_ - 1) xf[pair0 + own] = xn;
            }
        }

        if (grid_bar_old(bar, gid, (unsigned)(2 * t + 2), &abort_s)) break;
    }
}

// ======================= fallback path (known-good) =======================
__global__ __launch_bounds__(256) void gemm_step(const unsigned short* __restrict__ Wb,
                                                 const unsigned short* __restrict__ rB,
                                                 float* __restrict__ P)
{
    __shared__ unsigned short A_lds[32768];

    const int tid = threadIdx.x;
    const int l   = tid & 63;
    const int w   = tid >> 6;
    const int m   = l & 15;
    const int q   = l >> 4;
    const int ig  = blockIdx.x >> 7;
    const int c   = blockIdx.x & 127;
    const int i0  = ig << 6;

    {
        const unsigned short* src = Wb + (size_t)(i0 + (w << 4) + m) * KTOT
                                       + (c << 9) + (q << 3);
        unsigned short* dst = &A_lds[(w << 13) + (l << 3)];
        #pragma unroll
        for (int kc = 0; kc < 16; ++kc) {
            uint4 v = *(const uint4*)(src + (kc << 5));
            *(uint4*)(dst + (kc << 9)) = v;
        }
    }

    const int b = (w << 4) + m;
    const float rj0 = bf2f(rB[b * HID_ + 2 * c]);
    const float rj1 = bf2f(rB[b * HID_ + 2 * c + 1]);
    const unsigned short* rrow = rB + b * HID_ + (q << 3);

    floatx4 acc0 = {0.f, 0.f, 0.f, 0.f};
    floatx4 acc1 = {0.f, 0.f, 0.f, 0.f};
    floatx4 acc2 = {0.f, 0.f, 0.f, 0.f};
    floatx4 acc3 = {0.f, 0.f, 0.f, 0.f};

    __syncthreads();

    #pragma unroll
    for (int kc = 0; kc < 16; ++kc) {
        const float rj = (kc < 8) ? rj0 : rj1;
        const uint4 rv = *(const uint4*)(rrow + ((kc & 7) << 5));
        short8 gfrag;
        {
            unsigned int* gp = (unsigned int*)&gfrag;
            const unsigned short* rs = (const unsigned short*)&rv;
            #pragma unroll
            for (int p = 0; p < 4; ++p) {
                const float lo = bf2f(rs[2 * p])     * rj;
                const float hi = bf2f(rs[2 * p + 1]) * rj;
                gp[p] = (unsigned int)f2bf(lo) | ((unsigned int)f2bf(hi) << 16);
            }
        }
        const unsigned short* ab = &A_lds[(kc << 9) + (l << 3)];
        const short8 w0 = *(const short8*)(ab);
        const short8 w1 = *(const short8*)(ab + 8192);
        const short8 w2 = *(const short8*)(ab + 16384);
        const short8 w3 = *(const short8*)(ab + 24576);
        acc0 = __builtin_amdgcn_mfma_f32_16x16x32_bf16(gfrag, w0, acc0, 0, 0, 0);
        acc1 = __builtin_amdgcn_mfma_f32_16x16x32_bf16(gfrag, w1, acc1, 0, 0, 0);
        acc2 = __builtin_amdgcn_mfma_f32_16x16x32_bf16(gfrag, w2, acc2, 0, 0, 0);
        acc3 = __builtin_amdgcn_mfma_f32_16x16x32_bf16(gfrag, w3, acc3, 0, 0, 0);
    }

    #pragma unroll
    for (int reg = 0; reg < 4; ++reg) {
        float* dst = P + (c << 14) + ((w << 4) + (q << 2) + reg) * HID_ + i0 + m;
        dst[0]  = acc0[reg];
        dst[16] = acc1[reg];
        dst[32] = acc2[reg];
        dst[48] = acc3[reg];
    }
}

__global__ __launch_bounds__(64) void combine_step(const float* __restrict__ P,
                                                   const float* __restrict__ noise,
                                                   const float* __restrict__ u,
                                                   const float* __restrict__ W_inT,
                                                   const float* __restrict__ b_in,
                                                   float* __restrict__ x,
                                                   unsigned short* __restrict__ rB,
                                                   float* __restrict__ traj,
                                                   int t)
{
    const int b = blockIdx.x >> 2;
    const int i = ((blockIdx.x & 3) << 6) + threadIdx.x;

    __shared__ float u_s[64];
    u_s[threadIdx.x] = u[b * (T_ * IN_) + t * IN_ + threadIdx.x];
    __syncthreads();

    const float* Pp = P + b * HID_ + i;
    float s0 = 0.f, s1 = 0.f, s2 = 0.f, s3 = 0.f;
    #pragma unroll 4
    for (int cc = 0; cc < 128; cc += 4) {
        s0 += Pp[(cc + 0) * 16384];
        s1 += Pp[(cc + 1) * 16384];
        s2 += Pp[(cc + 2) * 16384];
        s3 += Pp[(cc + 3) * 16384];
    }
    const float hidden = (s0 + s1) + (s2 + s3);

    float inp = b_in[i];
    #pragma unroll
    for (int k = 0; k < 64; ++k) inp += u_s[k] * W_inT[k * HID_ + i];

    const float xo = x[b * HID_ + i];
    const float n  = noise[t * (B_ * HID_) + b * HID_ + i];
    const float xn = 0.8f * xo + 0.05f * n + 0.2f * (hidden + inp);

    x[b * HID_ + i] = xn;
    traj[(size_t)b * (T_ * HID_) + t * HID_ + i] = xn;
    rB[b * HID_ + i] = f2bf(tanhf(xn));
}

__global__ __launch_bounds__(256) void copy_xfinal(const float* __restrict__ x,
                                                   float* __restrict__ xf)
{
    const int idx = blockIdx.x * 256 + threadIdx.x;
    xf[idx] = x[idx];
}

// ---- output projection (fp32) --------------------------------------------
__global__ __launch_bounds__(256) void output_kernel(const float* __restrict__ traj,
                                                     const float* __restrict__ W_out,
                                                     const float* __restrict__ b_out,
                                                     float* __restrict__ out)
{
    __shared__ float r_s[16 * 256];
    __shared__ float Wt[64 * 65];

    const int tid = threadIdx.x;
    const int b   = blockIdx.x >> 5;
    const int t0  = (blockIdx.x & 31) << 4;

    #pragma unroll
    for (int r = 0; r < 16; ++r) {
        r_s[r * 256 + tid] = tanhf(traj[(size_t)b * (T_ * HID_) + (t0 + r) * HID_ + tid]);
    }

    const int o  = tid & 63;
    const int rg = tid >> 6;
    float acc0 = b_out[o];
    float acc1 = acc0, acc2 = acc0, acc3 = acc0;

    for (int ib = 0; ib < 4; ++ib) {
        __syncthreads();
        #pragma unroll
        for (int r = 0; r < 16; ++r) {
            const int f  = (r << 8) + tid;
            const int oo = f >> 6;
            const int il = f & 63;
            Wt[il * 65 + oo] = W_out[oo * 256 + (ib << 6) + il];
        }
        __syncthreads();
        #pragma unroll 16
        for (int il = 0; il < 64; ++il) {
            const float ww = Wt[il * 65 + o];
            const int i = (ib << 6) + il;
            acc0 += r_s[(rg * 4 + 0) * 256 + i] * ww;
            acc1 += r_s[(rg * 4 + 1) * 256 + i] * ww;
            acc2 += r_s[(rg * 4 + 2) * 256 + i] * ww;
            acc3 += r_s[(rg * 4 + 3) * 256 + i] * ww;
        }
    }
    float* ob = out + b * (T_ * IN_) + (t0 + (rg << 2)) * IN_ + o;
    ob[0 * IN_] = acc0;
    ob[1 * IN_] = acc1;
    ob[2 * IN_] = acc2;
    ob[3 * IN_] = acc3;
}

extern "C" void kernel_launch(void* const* d_in, const int* in_sizes, int n_in,
                              void* d_out, int out_size, void* d_ws, size_t ws_size,
                              hipStream_t stream)
{
    const float* u     = (const float*)d_in[0];
    const float* x0    = (const float*)d_in[1];
    const float* noise = (const float*)d_in[2];
    const float* W_hh  = (const float*)d_in[3];
    const float* W_in  = (const float*)d_in[4];
    const float* b_in  = (const float*)d_in[5];
    const float* W_out = (const float*)d_in[6];
    const float* b_out = (const float*)d_in[7];

    float* out  = (float*)d_out;
    float* xf   = out + 2097152;            // [B][HID]
    float* traj = out + 2097152 + 16384;    // [B][T][HID]

    // ws byte layout (shared by all tiers):
    //   P     : 0           (8 MB region; coop uses first 2 MB)
    //   ring  : 8,388,608   (1024 x 32768 = 33,554,432)  [coop; fb Wb overlaps]
    //   W_inT : 41,943,040  (65,536)
    //   bar   : 42,008,576  (8,192 = 2048 uints)
    //   rB_fb : 42,016,768  (32,768)                     [fallback]
    //   x_fb  : 42,049,536  (65,536)                     [fallback]
    //   pre   : 42,115,072  (33,554,432)                 [optional]
    char* wsb = (char*)d_ws;
    float*          P     = (float*)(wsb);
    unsigned short* ring  = (unsigned short*)(wsb + 8388608ull);
    unsigned short* Wb    = (unsigned short*)(wsb + 8388608ull);
    float*          W_inT = (float*)(wsb + 41943040ull);
    unsigned*       bar   = (unsigned*)(wsb + 42008576ull);
    unsigned short* rB_fb = (unsigned short*)(wsb + 42016768ull);
    float*          x     = (float*)(wsb + 42049536ull);
    float*          pre   = (float*)(wsb + 42115072ull);
    const int use_pre = (ws_size >= 42115072ull + 33554432ull) ? 1 : 0;

    init_kernel<<<64, 256, 0, stream>>>(x0, W_in, ring, W_inT, bar);
    if (use_pre) pre_kernel<<<256, 256, 0, stream>>>(u, W_inT, b_in, noise, pre);

    // ---- tier1: persist4 (decontended barriers + pre prefetch) ----
    {
        const float*          a_W    = W_hh;
        unsigned short*       a_ring = ring;
        float*                a_P    = P;
        const float*          a_pre  = pre;
        const float*          a_u    = u;
        const float*          a_WinT = W_inT;
        const float*          a_bin  = b_in;
        const float*          a_nz   = noise;
        const float*          a_x0   = x0;
        float*                a_traj = traj;
        float*                a_xf   = xf;
        unsigned*             a_bar  = bar;
        int                   a_up   = use_pre;
        void* args[] = { &a_W, &a_ring, &a_P, &a_pre, &a_u, &a_WinT, &a_bin,
                         &a_nz, &a_x0, &a_traj, &a_xf, &a_bar, &a_up };
        hipError_t e = hipLaunchCooperativeKernel(persist4, dim3(512), dim3(256),
                                                  args, 0, stream);
        if (e == hipSuccess) {
            output_kernel<<<2048, 256, 0, stream>>>(traj, W_out, b_out, out);
            return;
        }
    }

    // ---- tier2: R4 proven coop kernel ----
    {
        const float*          a_W    = W_hh;
        unsigned short*       a_ring = ring;
        float*                a_P    = P;
        const float*          a_pre  = pre;
        const float*          a_u    = u;
        const float*          a_WinT = W_inT;
        const float*          a_bin  = b_in;
        const float*          a_nz   = noise;
        const float*          a_x0   = x0;
        float*                a_traj = traj;
        float*                a_xf   = xf;
        unsigned*             a_bar  = bar;
        int                   a_up   = use_pre;
        void* args[] = { &a_W, &a_ring, &a_P, &a_pre, &a_u, &a_WinT, &a_bin,
                         &a_nz, &a_x0, &a_traj, &a_xf, &a_bar, &a_up };
        hipError_t e = hipLaunchCooperativeKernel(persist_kernel, dim3(512), dim3(256),
                                                  args, 0, stream);
        if (e == hipSuccess) {
            output_kernel<<<2048, 256, 0, stream>>>(traj, W_out, b_out, out);
            return;
        }
    }

    // ---- fallback: per-step launches (known-good path) ----
    {
        conv_w<<<16384, 256, 0, stream>>>(W_hh, Wb);   // clobbers ring
        init_kernel<<<64, 256, 0, stream>>>(x0, W_in, rB_fb, W_inT, bar);
        init_x<<<64, 256, 0, stream>>>(x0, x);
        for (int t = 0; t < T_; ++t) {
            gemm_step<<<512, 256, 0, stream>>>(Wb, rB_fb, P);
            combine_step<<<256, 64, 0, stream>>>(P, noise, u, W_inT, b_in, x, rB_fb, traj, t);
        }
        copy_xfinal<<<64, 256, 0, stream>>>(x, xf);
        output_kernel<<<2048, 256, 0, stream>>>(traj, W_out, b_out, out);
    }
}

// Round 8
// 3977.309 us; speedup vs baseline: 1.6054x; 1.1918x over previous
//
#include <hip/hip_runtime.h>
#include <math.h>

#define B_   64
#define T_   512
#define IN_  64
#define HID_ 256
#define KTOT 65536   // HID*HID

typedef __attribute__((ext_vector_type(8))) short  short8;
typedef __attribute__((ext_vector_type(4))) float  floatx4;

__device__ __forceinline__ unsigned short f2bf(float f) {
    unsigned int u = __float_as_uint(f);
    u += 0x7FFFu + ((u >> 16) & 1u);          // round-to-nearest-even
    return (unsigned short)(u >> 16);
}
__device__ __forceinline__ float bf2f(unsigned short s) {
    return __uint_as_float(((unsigned int)s) << 16);
}

// coherent (agent-scope, cache-bypassing -> memory-side LLC) accesses
__device__ __forceinline__ void cstore(float* p, float v) {
    __hip_atomic_store(p, v, __ATOMIC_RELAXED, __HIP_MEMORY_SCOPE_AGENT);
}
__device__ __forceinline__ float cload(const float* p) {
    return __hip_atomic_load((float*)p, __ATOMIC_RELAXED, __HIP_MEMORY_SCOPE_AGENT);
}
__device__ __forceinline__ void cstore_u32(unsigned* p, unsigned v) {
    __hip_atomic_store(p, v, __ATOMIC_RELAXED, __HIP_MEMORY_SCOPE_AGENT);
}

// ring slot permutation: bit-reverse(10b) -> consecutive t are >=16MB apart,
// defeating any sequential prefetch that could cache a not-yet-written slot.
__device__ __forceinline__ size_t slot_off(int t) {
    return (size_t)(__brev((unsigned)t) >> 22) << 14;   // ushort offset
}

// ---- fallback only: W_hh fp32 -> bf16 ------------------------------------
__global__ __launch_bounds__(256) void conv_w(const float* __restrict__ W,
                                              unsigned short* __restrict__ Wb)
{
    const size_t idx = ((size_t)blockIdx.x * 256 + threadIdx.x) * 4;
    const float4 v = *(const float4*)(W + idx);
    unsigned int lo = (unsigned int)f2bf(v.x) | ((unsigned int)f2bf(v.y) << 16);
    unsigned int hi = (unsigned int)f2bf(v.z) | ((unsigned int)f2bf(v.w) << 16);
    *(uint2*)(Wb + idx) = make_uint2(lo, hi);
}

// ---- init: rB/ring-slot0 (bf16), W_inT, zero barrier (2048 uints) --------
__global__ __launch_bounds__(256) void init_kernel(const float* __restrict__ x0,
                                                   const float* __restrict__ W_in,
                                                   unsigned short* __restrict__ rB,
                                                   float* __restrict__ W_inT,
                                                   unsigned* __restrict__ bar)
{
    const int b = blockIdx.x;   // doubles as k for W_inT (both 64)
    const int i = threadIdx.x;
    rB[b * HID_ + i] = f2bf(tanhf(x0[b * HID_ + i]));
    W_inT[b * HID_ + i] = W_in[i * IN_ + b];
    if (b == 0) {
        for (int j2 = i; j2 < 2048; j2 += 256) bar[j2] = 0u;
    }
}

// fallback-only: x state buffer init
__global__ __launch_bounds__(256) void init_x(const float* __restrict__ x0,
                                              float* __restrict__ x)
{
    const int idx = blockIdx.x * 256 + threadIdx.x;
    x[idx] = x0[idx];
}

// ---- precompute: pre[t][b][i] = 0.05*n + 0.2*(b_in + u@W_in^T) -----------
__global__ __launch_bounds__(256) void pre_kernel(const float* __restrict__ u,
                                                  const float* __restrict__ W_inT,
                                                  const float* __restrict__ b_in,
                                                  const float* __restrict__ noise,
                                                  float* __restrict__ pre)
{
    __shared__ float u_s[4][64];
    const int i  = threadIdx.x;
    const int b  = blockIdx.x >> 2;
    const int t0 = (blockIdx.x & 3) << 7;
    float wcol[64];
    #pragma unroll
    for (int k = 0; k < 64; ++k) wcol[k] = W_inT[(k << 8) + i];
    const float bi = b_in[i];
    for (int tt = 0; tt < 128; tt += 4) {
        __syncthreads();
        u_s[i >> 6][i & 63] = u[b * (T_ * IN_) + (t0 + tt + (i >> 6)) * IN_ + (i & 63)];
        __syncthreads();
        #pragma unroll
        for (int j2 = 0; j2 < 4; ++j2) {
            const int t = t0 + tt + j2;
            float acc = bi;
            #pragma unroll
            for (int k = 0; k < 64; ++k) acc = fmaf(u_s[j2][k], wcol[k], acc);
            pre[t * 16384 + b * HID_ + i] =
                fmaf(0.05f, noise[t * 16384 + b * HID_ + i], 0.2f * acc);
        }
    }
}

// ---- barriers -------------------------------------------------------------
// persist5 bar layout (uint idx, stride >=16 => >=64B line separation):
//   [g*32]        g<16 : bar1 per-ig counters (16 arrivals)
//   [512+g*32]    g<16 : bar1 per-ig flags
//   [1024+g*32]   g<16 : bar2 group counters (16 arrivals)
//   [1536]             : bar2 root counter (16 arrivals)
//   [1568+g*16]   g<16 : bar2 distributed release flags
//   [1824]             : poison flag
// persist4 (tier2) reuses [512..1536] region with its own meaning; tiers are
// mutually exclusive and bar is zeroed before either runs.
#define POISON_IDX 1824

__device__ __forceinline__ int spin_flag(unsigned* bar, int flag_idx, unsigned ep)
{
    int poison = 0;
    unsigned spins = 0;
    for (;;) {
        const unsigned f = __hip_atomic_load(&bar[flag_idx], __ATOMIC_RELAXED,
                                             __HIP_MEMORY_SCOPE_AGENT);
        if (f >= ep) break;
        if ((spins & 63u) == 0u) {
            if (__hip_atomic_load(&bar[POISON_IDX], __ATOMIC_RELAXED,
                                  __HIP_MEMORY_SCOPE_AGENT) != 0u) {
                poison = 1; break;
            }
        }
        if (++spins > 1000000u) {    // bounded: poison all, abort cleanly
            __hip_atomic_store(&bar[POISON_IDX], 1u, __ATOMIC_RELAXED,
                               __HIP_MEMORY_SCOPE_AGENT);
            poison = 1; break;
        }
        __builtin_amdgcn_s_sleep(1);
    }
    return poison;
}

// persist5 bar1: 16-block sub-barrier among same-ig blocks (producer set ==
// consumer set). Localized jitter, 16-wide max-reduction.
__device__ __forceinline__ int bar1_ig(unsigned* bar, int g, unsigned ep,
                                       int* abort_s)
{
    __syncthreads();                     // drains vmcnt: P cstores retired
    if (threadIdx.x == 0) {
        const unsigned a = __hip_atomic_fetch_add(&bar[g * 32], 1u,
                               __ATOMIC_RELAXED, __HIP_MEMORY_SCOPE_AGENT);
        if (a == ep * 16u - 1u)
            __hip_atomic_store(&bar[512 + g * 32], ep, __ATOMIC_RELAXED,
                               __HIP_MEMORY_SCOPE_AGENT);
        *abort_s = spin_flag(bar, 512 + g * 32, ep);
    }
    __syncthreads();
    return *abort_s;
}

// persist5 bar2: global, 2-level (16 groups x 16), distributed release flags
__device__ __forceinline__ int bar2_all(unsigned* bar, int g, unsigned ep,
                                        int* abort_s)
{
    __syncthreads();                     // drains vmcnt: ring cstores retired
    if (threadIdx.x == 0) {
        const unsigned a = __hip_atomic_fetch_add(&bar[1024 + g * 32], 1u,
                               __ATOMIC_RELAXED, __HIP_MEMORY_SCOPE_AGENT);
        if (a == ep * 16u - 1u) {
            const unsigned r = __hip_atomic_fetch_add(&bar[1536], 1u,
                                   __ATOMIC_RELAXED, __HIP_MEMORY_SCOPE_AGENT);
            if (r == ep * 16u - 1u) {
                #pragma unroll
                for (int gg = 0; gg < 16; ++gg)
                    __hip_atomic_store(&bar[1568 + gg * 16], ep, __ATOMIC_RELAXED,
                                       __HIP_MEMORY_SCOPE_AGENT);
            }
        }
        *abort_s = spin_flag(bar, 1568 + g * 16, ep);
    }
    __syncthreads();
    return *abort_s;
}

// ---- persist5: 256 blocks x 512 thr (8 waves), 1 block/CU ----------------
// Block (ig,kg4): i-range [ig*16,+16), j-range [kg4*16,+16).
// Wave w owns j-pair j0 = kg4*16+2w; W slice in VGPR (wv[16] = 64 regs/lane).
// Per step: stage r (ring slot bitrev(t), plain cached uint4; write-once
// discipline proven R6/R7) into swizzled rL (ONE copy per CU); MFMA; 8-wave
// LDS reduce; wave0 cstores P[kg4] (16 slices, 1 MB/step). bar1 = per-ig
// 16-block sub-barrier. Phase C: block owns pairs b in [4kg4,+4) x i in
// [16ig,+16) -> reads ONLY own-ig slices; 2 cloads/thread -> red[8][64];
// wave0 sums, updates x, cstores r into slot bitrev(t+1), writes traj.
// bar2 global. pre[t+1] prefetched in wave0 registers across bar2.
__global__ __launch_bounds__(512, 1) void persist5(
    const float* __restrict__ W_hh,
    unsigned short* __restrict__ ring,   // 1024 slots x 16384 ushorts (32 MB)
    float* __restrict__ P,               // [16][64][256] f32 (1 MB)
    const float* __restrict__ pre,
    const float* __restrict__ u,
    const float* __restrict__ W_inT,
    const float* __restrict__ b_in,
    const float* __restrict__ noise,
    const float* __restrict__ x0,
    float* __restrict__ traj,
    float* __restrict__ xf,
    unsigned* bar,
    int use_pre)
{
    __shared__ unsigned short rL[16384];     // 32 KB swizzled r[64 b][256 k]
    __shared__ float Wr[7][4][64][4];        // 28 KB wave partials (waves 1..7)
    __shared__ float red[8][64];             // 2 KB phase-C partials
    __shared__ int abort_s;

    const int tid = threadIdx.x;     // 0..511
    const int l   = tid & 63;
    const int w   = tid >> 6;        // wave 0..7
    const int m   = l & 15;
    const int q   = l >> 4;
    const int blk = blockIdx.x;      // 0..255
    const int ig  = blk >> 4;        // 0..15
    const int kg4 = blk & 15;        // 0..15
    const int i0  = ig << 4;
    const int j0  = (kg4 << 4) + (w << 1);  // this wave's even j (0..254)

    // ---- W residency: fp32 -> bf16 into 16 x short8 (64 VGPR) ----
    short8 wv[16];
    {
        const float* s0 = W_hh + (size_t)(i0 + m) * KTOT + (j0 << 8) + (q << 3);
        #pragma unroll
        for (int kc = 0; kc < 8; ++kc) {
            #pragma unroll
            for (int half = 0; half < 2; ++half) {
                const float* sp = s0 + (half << 8) + (kc << 5);
                const float4 a  = *(const float4*)(sp);
                const float4 bv = *(const float4*)(sp + 4);
                unsigned* gp = (unsigned*)&wv[kc + (half << 3)];
                gp[0] = (unsigned)f2bf(a.x)  | ((unsigned)f2bf(a.y)  << 16);
                gp[1] = (unsigned)f2bf(a.z)  | ((unsigned)f2bf(a.w)  << 16);
                gp[2] = (unsigned)f2bf(bv.x) | ((unsigned)f2bf(bv.y) << 16);
                gp[3] = (unsigned)f2bf(bv.z) | ((unsigned)f2bf(bv.w) << 16);
            }
        }
    }

    // phase-C ownership (wave0 lane p): b = 4*kg4 + p>>4, i = i0 + (p&15)
    const int p       = l;
    const int cb      = (kg4 << 2) + (p >> 4);
    const int ci      = i0 + (p & 15);
    const int pairIdx = (cb << 8) + ci;
    float x_reg = (w == 0) ? x0[pairIdx] : 0.f;

    float pn_pref = 0.f;
    if (use_pre && w == 0) pn_pref = pre[pairIdx];

    const int g = ig;                // group id for both bar1 and bar2
    const floatx4 z4 = {0.f, 0.f, 0.f, 0.f};

    for (int t = 0; t < T_; ++t) {
        // ---- stage r (ring slot bitrev(t)) -> rL; 4 x uint4 per thread ----
        {
            const uint4* src = (const uint4*)(ring + slot_off(t));
            #pragma unroll
            for (int j2 = 0; j2 < 4; ++j2) {
                const int u4  = (j2 << 9) + tid;       // 0..2047
                const uint4 v = src[u4];
                const int row = u4 >> 5;               // 0..63
                const int c8  = (u4 & 31) << 3;        // ushort col, 8-aligned
                *(uint4*)&rL[(row << 8) + (c8 ^ ((row & 7) << 3))] = v;
            }
        }
        __syncthreads();

        // ---- phase G: partial D[64][16] over j0, j0+1 ----
        floatx4 aA[4], aB[4];
        #pragma unroll
        for (int mt = 0; mt < 4; ++mt) { aA[mt] = z4; aB[mt] = z4; }

        #pragma unroll
        for (int kc = 0; kc < 8; ++kc) {
            const int cc = (q << 3) + (kc << 5);
            #pragma unroll
            for (int mt = 0; mt < 4; ++mt) {
                const int row = (mt << 4) + m;
                const short8 af = *(const short8*)&rL[(row << 8) + (cc ^ ((row & 7) << 3))];
                aA[mt] = __builtin_amdgcn_mfma_f32_16x16x32_bf16(af, wv[kc],     aA[mt], 0, 0, 0);
                aB[mt] = __builtin_amdgcn_mfma_f32_16x16x32_bf16(af, wv[kc + 8], aB[mt], 0, 0, 0);
            }
        }

        // output-side r_j scaling (fp32)
        floatx4 pd[4];
        #pragma unroll
        for (int mt = 0; mt < 4; ++mt) {
            #pragma unroll
            for (int reg = 0; reg < 4; ++reg) {
                const int b = (mt << 4) + (q << 2) + reg;
                const unsigned rr = *(const unsigned*)&rL[(b << 8) + (j0 ^ ((b & 7) << 3))];
                pd[mt][reg] = bf2f((unsigned short)(rr & 0xffffu)) * aA[mt][reg]
                            + bf2f((unsigned short)(rr >> 16))     * aB[mt][reg];
            }
        }

        // 8-wave reduce: waves 1..7 -> Wr, wave 0 sums + cstores P[kg4]
        if (w > 0) {
            #pragma unroll
            for (int mt = 0; mt < 4; ++mt) *(floatx4*)&Wr[w - 1][mt][l][0] = pd[mt];
        }
        __syncthreads();
        if (w == 0) {
            #pragma unroll
            for (int mt = 0; mt < 4; ++mt) {
                floatx4 s = pd[mt];
                #pragma unroll
                for (int k = 0; k < 7; ++k)
                    s += *(const floatx4*)&Wr[k][mt][l][0];
                #pragma unroll
                for (int reg = 0; reg < 4; ++reg) {
                    const int b = (mt << 4) + (q << 2) + reg;
                    cstore(&P[(kg4 << 14) + (b << 8) + i0 + m], s[reg]);
                }
            }
        }

        if (bar1_ig(bar, g, (unsigned)(t + 1), &abort_s)) break;

        // ---- phase C: 2 cloads/thread -> red, wave0 finishes ----
        {
            const int sp = tid >> 6;              // 0..7 (== w)
            const int pr = tid & 63;
            const int b2 = (kg4 << 2) + (pr >> 4);
            const int i2 = i0 + (pr & 15);
            const float* Pp = P + (size_t)(sp << 1) * 16384 + (b2 << 8) + i2;
            red[sp][pr] = cload(Pp) + cload(Pp + 16384);
        }
        __syncthreads();
        if (w == 0) {
            const float hidden = ((red[0][p] + red[1][p]) + (red[2][p] + red[3][p]))
                               + ((red[4][p] + red[5][p]) + (red[6][p] + red[7][p]));
            float pn;
            if (use_pre) {
                pn = pn_pref;
            } else {
                float inp = b_in[ci];
                const float* ur = u + cb * (T_ * IN_) + (t << 6);
                #pragma unroll
                for (int k = 0; k < 64; ++k)
                    inp = fmaf(ur[k], W_inT[(k << 8) + ci], inp);
                pn = fmaf(0.05f, noise[((size_t)t << 14) + pairIdx], 0.2f * inp);
            }
            const float xn = fmaf(0.8f, x_reg, fmaf(0.2f, hidden, pn));
            x_reg = xn;

            const unsigned short rb = f2bf(tanhf(xn));
            const unsigned nb = (unsigned)__shfl_xor((int)(unsigned)rb, 1, 64);
            if ((p & 1) == 0) {
                cstore_u32((unsigned*)(ring + slot_off(t + 1)) + (pairIdx >> 1),
                           ((unsigned)rb) | (nb << 16));
            }
            traj[(size_t)cb * (T_ * HID_) + (t << 8) + ci] = xn;
            if (t == T_ - 1) xf[pairIdx] = xn;
            if (use_pre && t + 1 < T_) pn_pref = pre[((t + 1) << 14) + pairIdx];
        }

        if (bar2_all(bar, g, (unsigned)(t + 1), &abort_s)) break;
    }
}

// ======== tier2: persist4 (proven 4.64 ms) — verbatim from R7 ==============
__device__ __forceinline__ int grid_bar1(unsigned* bar, int pg, int cg,
                                         unsigned ep, int* abort_s)
{
    __syncthreads();
    if (threadIdx.x == 0) {
        const unsigned a = __hip_atomic_fetch_add(&bar[pg * 32], 1u,
                               __ATOMIC_RELAXED, __HIP_MEMORY_SCOPE_AGENT);
        if (a == ep * 64u - 1u) {
            __hip_atomic_store(&bar[256 + pg * 32], ep, __ATOMIC_RELAXED,
                               __HIP_MEMORY_SCOPE_AGENT);
        }
        *abort_s = spin_flag(bar, 256 + cg * 32, ep);
    }
    __syncthreads();
    return *abort_s;
}

__device__ __forceinline__ int grid_bar2(unsigned* bar, int g2,
                                         unsigned ep, int* abort_s)
{
    __syncthreads();
    if (threadIdx.x == 0) {
        const unsigned a = __hip_atomic_fetch_add(&bar[512 + g2 * 32], 1u,
                               __ATOMIC_RELAXED, __HIP_MEMORY_SCOPE_AGENT);
        if (a == ep * 32u - 1u) {
            const unsigned r = __hip_atomic_fetch_add(&bar[1024], 1u,
                                   __ATOMIC_RELAXED, __HIP_MEMORY_SCOPE_AGENT);
            if (r == ep * 16u - 1u) {
                #pragma unroll
                for (int g = 0; g < 16; ++g)
                    __hip_atomic_store(&bar[1056 + g * 32], ep, __ATOMIC_RELAXED,
                                       __HIP_MEMORY_SCOPE_AGENT);
            }
        }
        *abort_s = spin_flag(bar, 1056 + g2 * 32, ep);
    }
    __syncthreads();
    return *abort_s;
}

__global__ __launch_bounds__(256, 2) void persist4(
    const float* __restrict__ W_hh,
    unsigned short* __restrict__ ring,
    float* __restrict__ P,
    const float* __restrict__ pre,
    const float* __restrict__ u,
    const float* __restrict__ W_inT,
    const float* __restrict__ b_in,
    const float* __restrict__ noise,
    const float* __restrict__ x0,
    float* __restrict__ traj,
    float* __restrict__ xf,
    unsigned* bar,
    int use_pre)
{
    __shared__ unsigned short rL[16384];
    __shared__ float Wr[3][4][64][4];
    __shared__ float red[128];
    __shared__ int abort_s;

    const int tid = threadIdx.x;
    const int l   = tid & 63;
    const int w   = tid >> 6;
    const int m   = l & 15;
    const int q   = l >> 4;
    const int blk = blockIdx.x;
    const int ig  = blk >> 5;
    const int kg  = blk & 31;
    const int i0  = ig << 4;
    const int j0  = (kg << 3) + (w << 1);

    const int pg = blk >> 6;
    const int cg = blk & 7;
    const int g2 = blk >> 5;

    short8 wv[16];
    {
        const float* s0 = W_hh + (size_t)(i0 + m) * KTOT + (j0 << 8) + (q << 3);
        #pragma unroll
        for (int kc = 0; kc < 8; ++kc) {
            #pragma unroll
            for (int half = 0; half < 2; ++half) {
                const float* sp = s0 + (half << 8) + (kc << 5);
                const float4 a  = *(const float4*)(sp);
                const float4 bv = *(const float4*)(sp + 4);
                unsigned* gp = (unsigned*)&wv[kc + (half << 3)];
                gp[0] = (unsigned)f2bf(a.x)  | ((unsigned)f2bf(a.y)  << 16);
                gp[1] = (unsigned)f2bf(a.z)  | ((unsigned)f2bf(a.w)  << 16);
                gp[2] = (unsigned)f2bf(bv.x) | ((unsigned)f2bf(bv.y) << 16);
                gp[3] = (unsigned)f2bf(bv.z) | ((unsigned)f2bf(bv.w) << 16);
            }
        }
    }

    const int own   = tid & 31;
    const int pair0 = blk << 5;
    const int sgrp  = tid >> 5;
    const int cb    = (pair0 + own) >> 8;
    const int ci    = (pair0 + own) & 255;
    float x_reg = x0[pair0 + own];

    const floatx4 z4 = {0.f, 0.f, 0.f, 0.f};

    float pn_pref = 0.f;
    if (use_pre) pn_pref = pre[pair0 + own];

    for (int t = 0; t < T_; ++t) {
        {
            const uint4* src = (const uint4*)(ring + slot_off(t));
            #pragma unroll
            for (int j2 = 0; j2 < 8; ++j2) {
                const int u4  = (j2 << 8) + tid;
                const uint4 v = src[u4];
                const int row = u4 >> 5;
                const int c8  = (u4 & 31) << 3;
                *(uint4*)&rL[(row << 8) + (c8 ^ ((row & 7) << 3))] = v;
            }
        }
        __syncthreads();

        floatx4 aA[4], aB[4];
        #pragma unroll
        for (int mt = 0; mt < 4; ++mt) { aA[mt] = z4; aB[mt] = z4; }

        #pragma unroll
        for (int kc = 0; kc < 8; ++kc) {
            const int cc = (q << 3) + (kc << 5);
            #pragma unroll
            for (int mt = 0; mt < 4; ++mt) {
                const int row = (mt << 4) + m;
                const short8 af = *(const short8*)&rL[(row << 8) + (cc ^ ((row & 7) << 3))];
                aA[mt] = __builtin_amdgcn_mfma_f32_16x16x32_bf16(af, wv[kc],     aA[mt], 0, 0, 0);
                aB[mt] = __builtin_amdgcn_mfma_f32_16x16x32_bf16(af, wv[kc + 8], aB[mt], 0, 0, 0);
            }
        }

        floatx4 pd[4];
        #pragma unroll
        for (int mt = 0; mt < 4; ++mt) {
            #pragma unroll
            for (int reg = 0; reg < 4; ++reg) {
                const int b = (mt << 4) + (q << 2) + reg;
                const unsigned rr = *(const unsigned*)&rL[(b << 8) + (j0 ^ ((b & 7) << 3))];
                pd[mt][reg] = bf2f((unsigned short)(rr & 0xffffu)) * aA[mt][reg]
                            + bf2f((unsigned short)(rr >> 16))     * aB[mt][reg];
            }
        }

        if (w > 0) {
            #pragma unroll
            for (int mt = 0; mt < 4; ++mt) *(floatx4*)&Wr[w - 1][mt][l][0] = pd[mt];
        }
        __syncthreads();
        if (w == 0) {
            #pragma unroll
            for (int mt = 0; mt < 4; ++mt) {
                floatx4 s = pd[mt];
                s += *(const floatx4*)&Wr[0][mt][l][0];
                s += *(const floatx4*)&Wr[1][mt][l][0];
                s += *(const floatx4*)&Wr[2][mt][l][0];
                #pragma unroll
                for (int reg = 0; reg < 4; ++reg) {
                    const int b = (mt << 4) + (q << 2) + reg;
                    cstore(&P[(kg << 14) + (b << 8) + i0 + m], s[reg]);
                }
            }
        }

        if (grid_bar1(bar, pg, cg, (unsigned)(t + 1), &abort_s)) break;

        {
            const float* Pp = P + (size_t)(sgrp << 2) * 16384 + pair0 + own;
            float part = cload(Pp) + cload(Pp + 16384)
                       + cload(Pp + 2 * 16384) + cload(Pp + 3 * 16384);
            part += __shfl_xor(part, 32, 64);
            if ((tid & 32) == 0) red[(w << 5) + own] = part;
            __syncthreads();
            const float hidden = red[own] + red[32 + own] + red[64 + own] + red[96 + own];

            float pn;
            if (use_pre) {
                pn = pn_pref;
            } else {
                float inp = b_in[ci];
                const float* ur = u + cb * (T_ * IN_) + (t << 6);
                #pragma unroll
                for (int k = 0; k < 64; ++k)
                    inp = fmaf(ur[k], W_inT[(k << 8) + ci], inp);
                pn = fmaf(0.05f, noise[((size_t)t << 14) + pair0 + own], 0.2f * inp);
            }
            const float xn = fmaf(0.8f, x_reg, fmaf(0.2f, hidden, pn));
            x_reg = xn;

            const unsigned short rb = f2bf(tanhf(xn));
            const unsigned nb = (unsigned)__shfl_xor((int)(unsigned)rb, 1, 64);
            if (tid < 32) {
                traj[(size_t)cb * (T_ * HID_) + (t << 8) + ci] = xn;
                if ((own & 1) == 0) {
                    cstore_u32((unsigned*)(ring + slot_off(t + 1))
                                   + ((pair0 + own) >> 1),
                               ((unsigned)rb) | (nb << 16));
                }
                if (t == T_ - 1) xf[pair0 + own] = xn;
            }
            if (use_pre && t + 1 < T_) pn_pref = pre[((t + 1) << 14) + pair0 + own];
        }

        if (grid_bar2(bar, g2, (unsigned)(t + 1), &abort_s)) break;
    }
}

// ======================= fallback path (known-good) =======================
__global__ __launch_bounds__(256) void gemm_step(const unsigned short* __restrict__ Wb,
                                                 const unsigned short* __restrict__ rB,
                                                 float* __restrict__ P)
{
    __shared__ unsigned short A_lds[32768];

    const int tid = threadIdx.x;
    const int l   = tid & 63;
    const int w   = tid >> 6;
    const int m   = l & 15;
    const int q   = l >> 4;
    const int ig  = blockIdx.x >> 7;
    const int c   = blockIdx.x & 127;
    const int i0  = ig << 6;

    {
        const unsigned short* src = Wb + (size_t)(i0 + (w << 4) + m) * KTOT
                                       + (c << 9) + (q << 3);
        unsigned short* dst = &A_lds[(w << 13) + (l << 3)];
        #pragma unroll
        for (int kc = 0; kc < 16; ++kc) {
            uint4 v = *(const uint4*)(src + (kc << 5));
            *(uint4*)(dst + (kc << 9)) = v;
        }
    }

    const int b = (w << 4) + m;
    const float rj0 = bf2f(rB[b * HID_ + 2 * c]);
    const float rj1 = bf2f(rB[b * HID_ + 2 * c + 1]);
    const unsigned short* rrow = rB + b * HID_ + (q << 3);

    floatx4 acc0 = {0.f, 0.f, 0.f, 0.f};
    floatx4 acc1 = {0.f, 0.f, 0.f, 0.f};
    floatx4 acc2 = {0.f, 0.f, 0.f, 0.f};
    floatx4 acc3 = {0.f, 0.f, 0.f, 0.f};

    __syncthreads();

    #pragma unroll
    for (int kc = 0; kc < 16; ++kc) {
        const float rj = (kc < 8) ? rj0 : rj1;
        const uint4 rv = *(const uint4*)(rrow + ((kc & 7) << 5));
        short8 gfrag;
        {
            unsigned int* gp = (unsigned int*)&gfrag;
            const unsigned short* rs = (const unsigned short*)&rv;
            #pragma unroll
            for (int pp = 0; pp < 4; ++pp) {
                const float lo = bf2f(rs[2 * pp])     * rj;
                const float hi = bf2f(rs[2 * pp + 1]) * rj;
                gp[pp] = (unsigned int)f2bf(lo) | ((unsigned int)f2bf(hi) << 16);
            }
        }
        const unsigned short* ab = &A_lds[(kc << 9) + (l << 3)];
        const short8 w0 = *(const short8*)(ab);
        const short8 w1 = *(const short8*)(ab + 8192);
        const short8 w2 = *(const short8*)(ab + 16384);
        const short8 w3 = *(const short8*)(ab + 24576);
        acc0 = __builtin_amdgcn_mfma_f32_16x16x32_bf16(gfrag, w0, acc0, 0, 0, 0);
        acc1 = __builtin_amdgcn_mfma_f32_16x16x32_bf16(gfrag, w1, acc1, 0, 0, 0);
        acc2 = __builtin_amdgcn_mfma_f32_16x16x32_bf16(gfrag, w2, acc2, 0, 0, 0);
        acc3 = __builtin_amdgcn_mfma_f32_16x16x32_bf16(gfrag, w3, acc3, 0, 0, 0);
    }

    #pragma unroll
    for (int reg = 0; reg < 4; ++reg) {
        float* dst = P + (c << 14) + ((w << 4) + (q << 2) + reg) * HID_ + i0 + m;
        dst[0]  = acc0[reg];
        dst[16] = acc1[reg];
        dst[32] = acc2[reg];
        dst[48] = acc3[reg];
    }
}

__global__ __launch_bounds__(64) void combine_step(const float* __restrict__ P,
                                                   const float* __restrict__ noise,
                                                   const float* __restrict__ u,
                                                   const float* __restrict__ W_inT,
                                                   const float* __restrict__ b_in,
                                                   float* __restrict__ x,
                                                   unsigned short* __restrict__ rB,
                                                   float* __restrict__ traj,
                                                   int t)
{
    const int b = blockIdx.x >> 2;
    const int i = ((blockIdx.x & 3) << 6) + threadIdx.x;

    __shared__ float u_s[64];
    u_s[threadIdx.x] = u[b * (T_ * IN_) + t * IN_ + threadIdx.x];
    __syncthreads();

    const float* Pp = P + b * HID_ + i;
    float s0 = 0.f, s1 = 0.f, s2 = 0.f, s3 = 0.f;
    #pragma unroll 4
    for (int cc = 0; cc < 128; cc += 4) {
        s0 += Pp[(cc + 0) * 16384];
        s1 += Pp[(cc + 1) * 16384];
        s2 += Pp[(cc + 2) * 16384];
        s3 += Pp[(cc + 3) * 16384];
    }
    const float hidden = (s0 + s1) + (s2 + s3);

    float inp = b_in[i];
    #pragma unroll
    for (int k = 0; k < 64; ++k) inp += u_s[k] * W_inT[k * HID_ + i];

    const float xo = x[b * HID_ + i];
    const float n  = noise[t * (B_ * HID_) + b * HID_ + i];
    const float xn = 0.8f * xo + 0.05f * n + 0.2f * (hidden + inp);

    x[b * HID_ + i] = xn;
    traj[(size_t)b * (T_ * HID_) + t * HID_ + i] = xn;
    rB[b * HID_ + i] = f2bf(tanhf(xn));
}

__global__ __launch_bounds__(256) void copy_xfinal(const float* __restrict__ x,
                                                   float* __restrict__ xf)
{
    const int idx = blockIdx.x * 256 + threadIdx.x;
    xf[idx] = x[idx];
}

// ---- output projection (fp32) --------------------------------------------
__global__ __launch_bounds__(256) void output_kernel(const float* __restrict__ traj,
                                                     const float* __restrict__ W_out,
                                                     const float* __restrict__ b_out,
                                                     float* __restrict__ out)
{
    __shared__ float r_s[16 * 256];
    __shared__ float Wt[64 * 65];

    const int tid = threadIdx.x;
    const int b   = blockIdx.x >> 5;
    const int t0  = (blockIdx.x & 31) << 4;

    #pragma unroll
    for (int r = 0; r < 16; ++r) {
        r_s[r * 256 + tid] = tanhf(traj[(size_t)b * (T_ * HID_) + (t0 + r) * HID_ + tid]);
    }

    const int o  = tid & 63;
    const int rg = tid >> 6;
    float acc0 = b_out[o];
    float acc1 = acc0, acc2 = acc0, acc3 = acc0;

    for (int ib = 0; ib < 4; ++ib) {
        __syncthreads();
        #pragma unroll
        for (int r = 0; r < 16; ++r) {
            const int f  = (r << 8) + tid;
            const int oo = f >> 6;
            const int il = f & 63;
            Wt[il * 65 + oo] = W_out[oo * 256 + (ib << 6) + il];
        }
        __syncthreads();
        #pragma unroll 16
        for (int il = 0; il < 64; ++il) {
            const float ww = Wt[il * 65 + o];
            const int i = (ib << 6) + il;
            acc0 += r_s[(rg * 4 + 0) * 256 + i] * ww;
            acc1 += r_s[(rg * 4 + 1) * 256 + i] * ww;
            acc2 += r_s[(rg * 4 + 2) * 256 + i] * ww;
            acc3 += r_s[(rg * 4 + 3) * 256 + i] * ww;
        }
    }
    float* ob = out + b * (T_ * IN_) + (t0 + (rg << 2)) * IN_ + o;
    ob[0 * IN_] = acc0;
    ob[1 * IN_] = acc1;
    ob[2 * IN_] = acc2;
    ob[3 * IN_] = acc3;
}

extern "C" void kernel_launch(void* const* d_in, const int* in_sizes, int n_in,
                              void* d_out, int out_size, void* d_ws, size_t ws_size,
                              hipStream_t stream)
{
    const float* u     = (const float*)d_in[0];
    const float* x0    = (const float*)d_in[1];
    const float* noise = (const float*)d_in[2];
    const float* W_hh  = (const float*)d_in[3];
    const float* W_in  = (const float*)d_in[4];
    const float* b_in  = (const float*)d_in[5];
    const float* W_out = (const float*)d_in[6];
    const float* b_out = (const float*)d_in[7];

    float* out  = (float*)d_out;
    float* xf   = out + 2097152;            // [B][HID]
    float* traj = out + 2097152 + 16384;    // [B][T][HID]

    // ws byte layout (shared by all tiers):
    //   P     : 0           (8 MB region; persist5 uses 1 MB, persist4 2 MB)
    //   ring  : 8,388,608   (1024 x 32768 = 33,554,432)  [coop; fb Wb overlaps]
    //   W_inT : 41,943,040  (65,536)
    //   bar   : 42,008,576  (8,192 = 2048 uints)
    //   rB_fb : 42,016,768  (32,768)                     [fallback]
    //   x_fb  : 42,049,536  (65,536)                     [fallback]
    //   pre   : 42,115,072  (33,554,432)                 [optional]
    char* wsb = (char*)d_ws;
    float*          P     = (float*)(wsb);
    unsigned short* ring  = (unsigned short*)(wsb + 8388608ull);
    unsigned short* Wb    = (unsigned short*)(wsb + 8388608ull);
    float*          W_inT = (float*)(wsb + 41943040ull);
    unsigned*       bar   = (unsigned*)(wsb + 42008576ull);
    unsigned short* rB_fb = (unsigned short*)(wsb + 42016768ull);
    float*          x     = (float*)(wsb + 42049536ull);
    float*          pre   = (float*)(wsb + 42115072ull);
    const int use_pre = (ws_size >= 42115072ull + 33554432ull) ? 1 : 0;

    init_kernel<<<64, 256, 0, stream>>>(x0, W_in, ring, W_inT, bar);
    if (use_pre) pre_kernel<<<256, 256, 0, stream>>>(u, W_inT, b_in, noise, pre);

    // ---- tier1: persist5 (256 blocks x 512 thr, 1/CU, local bar1) ----
    {
        const float*          a_W    = W_hh;
        unsigned short*       a_ring = ring;
        float*                a_P    = P;
        const float*          a_pre  = pre;
        const float*          a_u    = u;
        const float*          a_WinT = W_inT;
        const float*          a_bin  = b_in;
        const float*          a_nz   = noise;
        const float*          a_x0   = x0;
        float*                a_traj = traj;
        float*                a_xf   = xf;
        unsigned*             a_bar  = bar;
        int                   a_up   = use_pre;
        void* args[] = { &a_W, &a_ring, &a_P, &a_pre, &a_u, &a_WinT, &a_bin,
                         &a_nz, &a_x0, &a_traj, &a_xf, &a_bar, &a_up };
        hipError_t e = hipLaunchCooperativeKernel(persist5, dim3(256), dim3(512),
                                                  args, 0, stream);
        if (e == hipSuccess) {
            output_kernel<<<2048, 256, 0, stream>>>(traj, W_out, b_out, out);
            return;
        }
    }

    // ---- tier2: persist4 (proven R7, 4.64 ms) ----
    {
        const float*          a_W    = W_hh;
        unsigned short*       a_ring = ring;
        float*                a_P    = P;
        const float*          a_pre  = pre;
        const float*          a_u    = u;
        const float*          a_WinT = W_inT;
        const float*          a_bin  = b_in;
        const float*          a_nz   = noise;
        const float*          a_x0   = x0;
        float*                a_traj = traj;
        float*                a_xf   = xf;
        unsigned*             a_bar  = bar;
        int                   a_up   = use_pre;
        void* args[] = { &a_W, &a_ring, &a_P, &a_pre, &a_u, &a_WinT, &a_bin,
                         &a_nz, &a_x0, &a_traj, &a_xf, &a_bar, &a_up };
        hipError_t e = hipLaunchCooperativeKernel(persist4, dim3(512), dim3(256),
                                                  args, 0, stream);
        if (e == hipSuccess) {
            output_kernel<<<2048, 256, 0, stream>>>(traj, W_out, b_out, out);
            return;
        }
    }

    // ---- fallback: per-step launches (known-good path) ----
    {
        conv_w<<<16384, 256, 0, stream>>>(W_hh, Wb);   // clobbers ring
        init_kernel<<<64, 256, 0, stream>>>(x0, W_in, rB_fb, W_inT, bar);
        init_x<<<64, 256, 0, stream>>>(x0, x);
        for (int t = 0; t < T_; ++t) {
            gemm_step<<<512, 256, 0, stream>>>(Wb, rB_fb, P);
            combine_step<<<256, 64, 0, stream>>>(P, noise, u, W_inT, b_in, x, rB_fb, traj, t);
        }
        copy_xfinal<<<64, 256, 0, stream>>>(x, xf);
        output_kernel<<<2048, 256, 0, stream>>>(traj, W_out, b_out, out);
    }
}